// Round 7
// baseline (328.459 us; speedup 1.0000x reference)
//
#include <hip/hip_runtime.h>
#include <hip/hip_bf16.h>
#include <hip/hip_fp8.h>
#include <math.h>

#define N_NODES 100000
#define D_IN    128
#define D_HID   128
#define D_OUT   40
#define NBUCK   391      // ceil(100000/256), bucket = dst >> 8
#define CHUNK   4096     // edges per partition block (1024 threads, 4 edges/thread)
#define SLABCAP 16320    // per-bucket slab capacity (mean 8184, sigma~90 -> no overflow)
#define CAST_BLOCKS 6250 // (100000*128/8)/256

// ---------------- workspace layout (bytes) ----------------
// flag      : 0          (4)
// bcount    : 4096       (1564)
// deg       : 16384      (400,000 u32)
// invc      : 416,384    (400,000 f32)
// row_start : 816,384    (400,000 u32)
// csr       : 1,216,384  (12,800,000 i32)             ends 14,016,384
// xb (bf16) : 14,016,384 (25,600,000)                 ends 39,616,384
// aggb(bf16): 39,616,384 (25,600,000)                 ends 65,216,384
//   alias before aggb written: slab (u32, NBUCK*16320*4 = 25,524,480) @39,616,384
// wp1 (bf16): 65,216,384 (65,536)                     ends 65,281,920
// wp2 (bf16): 65,281,920 (20,480)                     ends 65,302,400 (pad to 65,310,720)
// pq  (fp8) : 65,310,720 (4,000,000)                  ends 69,310,720
// q   (f32) : 69,310,720 (16,000,000)                 ends 85,310,720
// xq  (fp8) : 90,910,720 (12,800,000)                 ends 103,710,720

using short8  = __attribute__((ext_vector_type(8))) short;
using float4v = __attribute__((ext_vector_type(4))) float;
using floatx2 = __attribute__((ext_vector_type(2))) float;

__device__ __forceinline__ unsigned short f2b(float f) {
    __hip_bfloat16 b = __float2bfloat16(f);
    return *(unsigned short*)&b;
}
__device__ __forceinline__ unsigned packb(float a, float b) {
    return (unsigned)f2b(a) | ((unsigned)f2b(b) << 16);
}

__device__ __forceinline__ unsigned char f2q(float f) {
    __hip_fp8_e4m3 v(f);
    return *(unsigned char*)&v;
}
template <int SEL>
__device__ __forceinline__ float q2f(unsigned u) {
#if __has_builtin(__builtin_amdgcn_cvt_f32_fp8)
    return __builtin_amdgcn_cvt_f32_fp8((int)u, SEL);
#else
    unsigned char b = (u >> (SEL * 8)) & 0xff;
    __hip_fp8_e4m3 v;
    *(unsigned char*)&v = b;
    return (float)v;
#endif
}
// packed: convert 2 fp8 to float2 in one instr
template <bool HI>
__device__ __forceinline__ floatx2 pkcvt(unsigned u) {
#if __has_builtin(__builtin_amdgcn_cvt_pk_f32_fp8)
    return __builtin_amdgcn_cvt_pk_f32_fp8((int)u, HI);
#else
    floatx2 r;
    if constexpr (HI) { r[0] = q2f<2>(u); r[1] = q2f<3>(u); }
    else              { r[0] = q2f<0>(u); r[1] = q2f<1>(u); }
    return r;
#endif
}

__device__ __forceinline__ long long edge_at(const void* ei, int is64, long long idx) {
    if (is64) return ((const long long*)ei)[idx];
    return (long long)((const int*)ei)[idx];
}

// Horizontal fusion: cast (blocks 0..6249) | pack_w (6250..6270) | detect+zero (6271)
__global__ __launch_bounds__(256) void prep_kernel(const float* __restrict__ x,
                                                   unsigned short* __restrict__ xb,
                                                   unsigned char* __restrict__ xq,
                                                   const float* __restrict__ W1l,
                                                   const float* __restrict__ W1r,
                                                   const float* __restrict__ W2l,
                                                   const float* __restrict__ W2r,
                                                   unsigned short* __restrict__ wp1,
                                                   unsigned short* __restrict__ wp2,
                                                   const int* __restrict__ ei,
                                                   int* __restrict__ flag,
                                                   unsigned* __restrict__ bcount) {
    const int b = blockIdx.x;
    if (b < CAST_BLOCKS) {
        // ---- cast: x (f32 [N,128]) -> xb (bf16) + xq (fp8 e4m3)
        long long i = ((long long)b * 256 + threadIdx.x) * 8;
        if (i >= (long long)N_NODES * 128) return;
        float4 a = *(const float4*)&x[i];
        float4 c = *(const float4*)&x[i + 4];
        ushort4 o0, o1;
        o0.x = f2b(a.x); o0.y = f2b(a.y); o0.z = f2b(a.z); o0.w = f2b(a.w);
        o1.x = f2b(c.x); o1.y = f2b(c.y); o1.z = f2b(c.z); o1.w = f2b(c.w);
        *(ushort4*)&xb[i] = o0;
        *(ushort4*)&xb[i + 4] = o1;
        uint2 p;
        p.x = (unsigned)f2q(a.x) | ((unsigned)f2q(a.y) << 8)
            | ((unsigned)f2q(a.z) << 16) | ((unsigned)f2q(a.w) << 24);
        p.y = (unsigned)f2q(c.x) | ((unsigned)f2q(c.y) << 8)
            | ((unsigned)f2q(c.z) << 16) | ((unsigned)f2q(c.w) << 24);
        *(uint2*)&xq[i] = p;
    } else if (b < CAST_BLOCKS + 21) {
        // ---- pack weights into MFMA B-fragment order (bf16)
        int t = (b - CAST_BLOCKS) * 256 + threadIdx.x;
        if (t < 4096) {                     // wp1 entries (ct,ks,lane)
            int lane = t & 63;
            int ks = (t >> 6) & 7;
            int ct = t >> 9;
            int n = ct * 16 + (lane & 15);
            int kr = (lane >> 4) * 8;
            unsigned short v[8];
#pragma unroll
            for (int j = 0; j < 8; ++j) {
                int k = ks * 32 + kr + j;
                float f = (k < 128) ? W1l[k * 128 + n] : W1r[(k - 128) * 128 + n];
                v[j] = f2b(f);
            }
            ushort4 o0 = {v[0], v[1], v[2], v[3]};
            ushort4 o1 = {v[4], v[5], v[6], v[7]};
            *(ushort4*)&wp1[t * 8] = o0;
            *(ushort4*)&wp1[t * 8 + 4] = o1;
        } else if (t < 4096 + 1280) {       // wp2 entries
            int u = t - 4096;
            int lane = u & 63;
            int ks = (u >> 6) & 3;
            int ct = u >> 8;
            int n = ct * 16 + (lane & 15);
            int kr = (lane >> 4) * 8;
            unsigned short v[8];
#pragma unroll
            for (int j = 0; j < 8; ++j) {
                int k = ks * 32 + kr + j;
                float f = (n < 40) ? W2l[k * 40 + n] : W2r[k * 40 + (n - 40)];
                v[j] = f2b(f);
            }
            ushort4 o0 = {v[0], v[1], v[2], v[3]};
            ushort4 o1 = {v[4], v[5], v[6], v[7]};
            *(ushort4*)&wp2[u * 8] = o0;
            *(ushort4*)&wp2[u * 8 + 4] = o1;
        }
    } else {
        // ---- detect int64 vs int32 edge_index (wave-parallel) + zero bcount
        const int t = threadIdx.x;
        if (t < 64) {
            int ok = 1;
#pragma unroll
            for (int k = 0; k < 4; ++k) {
                if (ei[2 * (t * 4 + k) + 1] != 0) ok = 0;
            }
            int all0 = __all(ok);
            if (t == 0) *flag = all0 ? 1 : 0;
        }
        if (t < NBUCK) bcount[t] = 0u;
        if (t + 256 < NBUCK) bcount[t + 256] = 0u;
    }
}

// Block-level LDS counting sort, then coalesced slab writes.
// 1024 threads, CHUNK=4096 edges/block. Scan via wave-level shfl (2 barriers, not 18).
__global__ __launch_bounds__(1024) void partition_kernel(const void* __restrict__ ei,
                                                         const int* __restrict__ flag,
                                                         unsigned* __restrict__ bcount,
                                                         unsigned* __restrict__ slab,
                                                         long long E) {
    __shared__ unsigned hist[NBUCK];     // counts, then cursor
    __shared__ unsigned lstart[NBUCK];   // local exclusive offsets
    __shared__ unsigned gofs[NBUCK];     // b*SLABCAP + gbase - lstart[b]
    __shared__ unsigned s[512];
    __shared__ unsigned ws[16];
    __shared__ unsigned rec[CHUNK];
    __shared__ unsigned short bkt[CHUNK];

    const int tid = threadIdx.x;
    const int lane = tid & 63;
    const int w = tid >> 6;              // wave 0..15
    const int is64 = *flag;
    const long long cb = (long long)blockIdx.x * CHUNK;
    const unsigned n = (unsigned)(((E - cb) < (long long)CHUNK) ? (E - cb) : CHUNK);

    if (tid < NBUCK) hist[tid] = 0;
    __syncthreads();

    // pass 1: histogram
#pragma unroll
    for (int j = 0; j < CHUNK / 1024; ++j) {
        unsigned e = j * 1024 + tid;
        if (e < n) {
            unsigned d = (unsigned)edge_at(ei, is64, E + cb + e);
            atomicAdd(&hist[d >> 8], 1u);
        }
    }
    __syncthreads();

    // inclusive scan of hist via wave shfl-scan + cross-wave fixup
    {
        unsigned v0 = (tid < NBUCK) ? hist[tid] : 0u;
        unsigned x = v0;
#pragma unroll
        for (int off = 1; off < 64; off <<= 1) {
            unsigned t = __shfl_up(x, off);
            if (lane >= off) x += t;
        }
        if (lane == 63) ws[w] = x;
        __syncthreads();
        if (w == 0) {
            unsigned y = (lane < 16) ? ws[lane] : 0u;
#pragma unroll
            for (int off = 1; off < 16; off <<= 1) {
                unsigned t = __shfl_up(y, off);
                if (lane >= off) y += t;
            }
            if (lane < 16) ws[lane] = y;
        }
        __syncthreads();
        unsigned pre = (w > 0) ? ws[w - 1] : 0u;
        if (tid < NBUCK) s[tid] = x + pre;   // inclusive scan
    }
    // s[tid] written by owning thread; consumed by same thread below.
    if (tid < NBUCK) {
        unsigned cnt = hist[tid];
        unsigned ex = s[tid] - cnt;
        lstart[tid] = ex;
        if (cnt) {
            unsigned g = atomicAdd(&bcount[tid], cnt);
            gofs[tid] = (unsigned)(tid * SLABCAP) + g - ex;
        }
        hist[tid] = 0;   // reuse as cursor
    }
    __syncthreads();

    // pass 2: scatter into LDS, bucket-grouped
#pragma unroll
    for (int j = 0; j < CHUNK / 1024; ++j) {
        unsigned e = j * 1024 + tid;
        if (e < n) {
            unsigned sv = (unsigned)edge_at(ei, is64, cb + e);
            unsigned d  = (unsigned)edge_at(ei, is64, E + cb + e);
            unsigned b = d >> 8;
            unsigned loc = atomicAdd(&hist[b], 1u);
            unsigned slot = lstart[b] + loc;
            rec[slot] = ((d & 255u) << 17) | sv;
            bkt[slot] = (unsigned short)b;
        }
    }
    __syncthreads();

    // pass 3: coalesced global writes (consecutive slots -> consecutive slab addrs per run)
#pragma unroll
    for (int j = 0; j < CHUNK / 1024; ++j) {
        unsigned i = j * 1024 + tid;
        if (i < n) {
            unsigned b = bkt[i];
            slab[gofs[b] + i] = rec[i];
        }
    }
}

// Per-bucket fine CSR build in LDS (reads slab, writes csr at prefix offsets).
// Inline exclusive prefix of bcount; wave-level reductions/scans.
__global__ __launch_bounds__(256) void build_kernel(const unsigned* __restrict__ slab,
                                                    const unsigned* __restrict__ bcount,
                                                    unsigned* __restrict__ deg,
                                                    float* __restrict__ invc,
                                                    unsigned* __restrict__ row_start,
                                                    int* __restrict__ csr) {
    __shared__ unsigned red[4];
    __shared__ unsigned ws[4];
    __shared__ unsigned cnt[256];
    const int tid = threadIdx.x;
    const int lane = tid & 63;
    const int w = tid >> 6;              // wave 0..3
    const int nb = blockIdx.x << 8;
    const long long sb = (long long)blockIdx.x * SLABCAP;

    // exclusive prefix: es = sum of bcount[0..blockIdx.x)
    unsigned pv = 0;
    for (unsigned i = tid; i < (unsigned)blockIdx.x; i += 256) pv += bcount[i];
#pragma unroll
    for (int off = 32; off >= 1; off >>= 1) pv += __shfl_xor(pv, off);
    if (lane == 0) red[w] = pv;
    __syncthreads();
    const unsigned es = red[0] + red[1] + red[2] + red[3];
    const unsigned n  = bcount[blockIdx.x];

    cnt[tid] = 0;
    __syncthreads();
    for (unsigned i = tid; i < n; i += 256) {
        unsigned d = slab[sb + i] >> 17;
        atomicAdd(&cnt[d], 1u);
    }
    __syncthreads();
    unsigned v = cnt[tid];
    // inclusive wave scan + cross-wave fixup
    unsigned x = v;
#pragma unroll
    for (int off = 1; off < 64; off <<= 1) {
        unsigned t = __shfl_up(x, off);
        if (lane >= off) x += t;
    }
    if (lane == 63) ws[w] = x;
    __syncthreads();
    unsigned pre = 0;
#pragma unroll
    for (int k = 0; k < 4; ++k) if (k < w) pre += ws[k];
    unsigned ex = x + pre - v;
    int node = nb + tid;
    if (node < N_NODES) {
        deg[node] = v;
        invc[node] = 1.0f / fmaxf((float)v, 1.0f);
        row_start[node] = es + ex;
    }
    __syncthreads();
    cnt[tid] = ex;   // reuse as cursor
    __syncthreads();
    for (unsigned i = tid; i < n; i += 256) {
        unsigned pr = slab[sb + i];
        unsigned d = pr >> 17;
        unsigned pos = es + atomicAdd(&cnt[d], 1u);
        csr[pos] = (int)(pr & 0x1FFFFu);
    }
}

// Gather-mean over 128 fp8 cols -> bf16 agg: one wave per node.
// Lane = (slot s = lane>>4, colgroup cg = lane&15): lane loads uint2 (8 fp8 cols) of
// neighbor j+s -> 4 neighbors per wave-load; packed cvt+add (2 elems/instr).
// Launched twice over half node-ranges (diagnostic split; total work identical).
__global__ __launch_bounds__(256) void gather_fp8_kernel(const unsigned char* __restrict__ featq,
                                                         const int* __restrict__ csr,
                                                         const unsigned* __restrict__ row_start,
                                                         const unsigned* __restrict__ deg,
                                                         const float* __restrict__ invc,
                                                         unsigned short* __restrict__ aggb,
                                                         int node0, int nend) {
    const int wave = threadIdx.x >> 6;
    const int lane = threadIdx.x & 63;
    const int node = node0 + blockIdx.x * 4 + wave;
    if (node >= nend) return;

    const unsigned start = row_start[node];
    const unsigned cnt = deg[node];
    const int s = lane >> 4;              // slot 0..3
    const unsigned cgo = (unsigned)((lane & 15) * 8);   // col-group byte offset

    floatx2 acc[4];
#pragma unroll
    for (int k = 0; k < 4; ++k) acc[k] = (floatx2){0.f, 0.f};

    for (unsigned base = 0; base < cnt; base += 64) {
        unsigned rem = cnt - base;
        if (rem > 64u) rem = 64u;
        int nid = (lane < (int)rem) ? csr[start + base + lane] : 0;
        for (unsigned j = 0; j < rem; j += 8) {
            uint2 u0 = {0u, 0u}, u1 = {0u, 0u};
            unsigned i0 = j + s;
            unsigned i1 = j + 4 + s;
            int s0 = __shfl(nid, (int)(i0 & 63));
            int s1 = __shfl(nid, (int)(i1 & 63));
            if (i0 < rem) u0 = *(const uint2*)&featq[((unsigned)s0 << 7) + cgo];
            if (i1 < rem) u1 = *(const uint2*)&featq[((unsigned)s1 << 7) + cgo];
            acc[0] += pkcvt<false>(u0.x); acc[1] += pkcvt<true>(u0.x);
            acc[2] += pkcvt<false>(u0.y); acc[3] += pkcvt<true>(u0.y);
            acc[0] += pkcvt<false>(u1.x); acc[1] += pkcvt<true>(u1.x);
            acc[2] += pkcvt<false>(u1.y); acc[3] += pkcvt<true>(u1.y);
        }
    }

    // reduce across the 4 slots (lanes differing in bits 4,5)
#pragma unroll
    for (int k = 0; k < 4; ++k) {
        acc[k][0] += __shfl_xor(acc[k][0], 16);
        acc[k][1] += __shfl_xor(acc[k][1], 16);
        acc[k][0] += __shfl_xor(acc[k][0], 32);
        acc[k][1] += __shfl_xor(acc[k][1], 32);
    }

    if (lane < 16) {
        const float ic = invc[node];
        uint4 o;
        o.x = packb(acc[0][0] * ic, acc[0][1] * ic);
        o.y = packb(acc[1][0] * ic, acc[1][1] * ic);
        o.z = packb(acc[2][0] * ic, acc[2][1] * ic);
        o.w = packb(acc[3][0] * ic, acc[3][1] * ic);
        *(uint4*)&aggb[(unsigned)node * 128u + cgo] = o;
    }
}

// Fused layer-1 GEMM + layer-2 projection: h = relu([aggb|xb]@wp1 + b1) stays in LDS,
// then [pq|q] = h@wp2 (+b2 on q half). 64 rows/block, 4 waves.
__global__ __launch_bounds__(256) void gemm12_kernel(const unsigned short* __restrict__ aggb,
                                                     const unsigned short* __restrict__ xb,
                                                     const unsigned short* __restrict__ wp1,
                                                     const float* __restrict__ b1,
                                                     const unsigned short* __restrict__ wp2,
                                                     const float* __restrict__ b2,
                                                     unsigned char* __restrict__ pq,
                                                     float* __restrict__ q) {
    __shared__ unsigned short sh[64][136];   // h rows (bf16), stride 272B (16B-aligned)
    const int wave = threadIdx.x >> 6;
    const int lane = threadIdx.x & 63;
    const int row0 = blockIdx.x * 64 + wave * 16;
    const unsigned abase = (unsigned)(row0 + (lane & 15)) * 128u + (unsigned)((lane >> 4) * 8);

    // ---- phase 1: h-strip via MFMA
    float4v acc[8];
#pragma unroll
    for (int ct = 0; ct < 8; ++ct) acc[ct] = (float4v){0.f, 0.f, 0.f, 0.f};

#pragma unroll
    for (int ks = 0; ks < 8; ++ks) {
        union { uint4 u; short8 s; } af;
        if (ks < 4) af.u = *(const uint4*)&aggb[abase + ks * 32];
        else        af.u = *(const uint4*)&xb[abase + (ks - 4) * 32];
#pragma unroll
        for (int ct = 0; ct < 8; ++ct) {
            union { uint4 u; short8 s; } bf;
            bf.u = *(const uint4*)&wp1[((ct * 8 + ks) * 64 + lane) * 8];
            acc[ct] = __builtin_amdgcn_mfma_f32_16x16x32_bf16(af.s, bf.s, acc[ct], 0, 0, 0);
        }
    }

    // relu+bias -> LDS (local rows of this wave's strip; no cross-wave sharing)
    const int lrow0 = wave * 16 + (lane >> 4) * 4;
    const int ccol = lane & 15;
#pragma unroll
    for (int ct = 0; ct < 8; ++ct) {
        const int col = ct * 16 + ccol;
        const float bv = b1[col];
#pragma unroll
        for (int r = 0; r < 4; ++r)
            sh[lrow0 + r][col] = f2b(fmaxf(acc[ct][r] + bv, 0.0f));
    }
    // wave-synchronous: each wave reads only rows it wrote; no __syncthreads needed.

    // ---- phase 2: [pq|q] strip via MFMA from LDS
    const unsigned short* aptr = &sh[wave * 16 + (lane & 15)][(lane >> 4) * 8];

    float4v acc2[5];
#pragma unroll
    for (int ct = 0; ct < 5; ++ct) acc2[ct] = (float4v){0.f, 0.f, 0.f, 0.f};

#pragma unroll
    for (int ks = 0; ks < 4; ++ks) {
        union { uint4 u; short8 s; } af;
        af.u = *(const uint4*)&aptr[ks * 32];
#pragma unroll
        for (int ct = 0; ct < 5; ++ct) {
            union { uint4 u; short8 s; } bf;
            bf.u = *(const uint4*)&wp2[((ct * 4 + ks) * 64 + lane) * 8];
            acc2[ct] = __builtin_amdgcn_mfma_f32_16x16x32_bf16(af.s, bf.s, acc2[ct], 0, 0, 0);
        }
    }

    const int crow0 = row0 + (lane >> 4) * 4;
#pragma unroll
    for (int ct = 0; ct < 5; ++ct) {
        const int col = ct * 16 + ccol;        // 0..79
#pragma unroll
        for (int r = 0; r < 4; ++r) {
            int row = crow0 + r;
            if (row < N_NODES) {
                if (col < D_OUT) {
                    pq[(unsigned)row * 40u + (unsigned)col] = f2q(acc2[ct][r]);
                } else {
                    q[(unsigned)row * 40u + (unsigned)(col - D_OUT)] = acc2[ct][r] + b2[col - D_OUT];
                }
            }
        }
    }
}

// out = log_softmax(meanagg(pq) + q): one wave per node.
// Lane = (slot s = lane/10, colgroup cg = lane%10): lane loads uint (4 fp8 cols) of
// neighbor j+s -> 6 neighbors per load instr; 3-deep unroll (18 neighbors/iter) —
// sized for deg~Poisson(32): less masked-slot waste than 4-deep.
__global__ __launch_bounds__(256) void gather40_kernel(const unsigned char* __restrict__ pq,
                                                       const float* __restrict__ q,
                                                       const int* __restrict__ csr,
                                                       const unsigned* __restrict__ row_start,
                                                       const unsigned* __restrict__ deg,
                                                       const float* __restrict__ invc,
                                                       float* __restrict__ out) {
    __shared__ float sm[4][40];
    const int wave = threadIdx.x >> 6;
    const int lane = threadIdx.x & 63;
    const int node = blockIdx.x * 4 + wave;
    if (node >= N_NODES) return;

    const unsigned start = row_start[node];
    const unsigned cnt = deg[node];
    const int s = lane / 10;          // 0..6 (6 -> idle)
    const int cg = lane % 10;         // col group (4 cols)
    const unsigned cgo = (unsigned)(cg * 4);
    const bool gactive = s < 6;

    floatx2 a01 = (floatx2){0.f, 0.f}, a23 = (floatx2){0.f, 0.f};

    for (unsigned base = 0; base < cnt; base += 64) {
        unsigned rem = cnt - base;
        if (rem > 64u) rem = 64u;
        int nid = (lane < (int)rem) ? csr[start + base + lane] : 0;
        for (unsigned j = 0; j < rem; j += 18) {
            unsigned u[3];
#pragma unroll
            for (int t = 0; t < 3; ++t) {
                unsigned idx = j + t * 6 + s;
                int sid = __shfl(nid, (int)(idx & 63));
                bool valid = gactive && (idx < rem);
                u[t] = valid ? *(const unsigned*)&pq[(unsigned)sid * 40u + cgo] : 0u;
            }
#pragma unroll
            for (int t = 0; t < 3; ++t) {
                a01 += pkcvt<false>(u[t]);
                a23 += pkcvt<true>(u[t]);
            }
        }
    }

    float a0 = a01[0], a1 = a01[1], a2 = a23[0], a3 = a23[1];
    // reduce slots 0..5 into slot 0 (lanes 0..9), guarded to avoid pollution
    {
        float t0, t1, t2, t3;
        t0 = __shfl(a0, lane + 30); t1 = __shfl(a1, lane + 30);
        t2 = __shfl(a2, lane + 30); t3 = __shfl(a3, lane + 30);
        if (lane < 30) { a0 += t0; a1 += t1; a2 += t2; a3 += t3; }
        t0 = __shfl(a0, lane + 20); t1 = __shfl(a1, lane + 20);
        t2 = __shfl(a2, lane + 20); t3 = __shfl(a3, lane + 20);
        if (lane < 10) { a0 += t0; a1 += t1; a2 += t2; a3 += t3; }
        t0 = __shfl(a0, lane + 10); t1 = __shfl(a1, lane + 10);
        t2 = __shfl(a2, lane + 10); t3 = __shfl(a3, lane + 10);
        if (lane < 10) { a0 += t0; a1 += t1; a2 += t2; a3 += t3; }
    }
    if (lane < 10) {
        sm[wave][cg * 4 + 0] = a0;
        sm[wave][cg * 4 + 1] = a1;
        sm[wave][cg * 4 + 2] = a2;
        sm[wave][cg * 4 + 3] = a3;
    }
    // wave-synchronous LDS round-trip (no barrier needed within a wave)
    const bool active = lane < D_OUT;
    float v = active ? (sm[wave][active ? lane : 0] * invc[node]
                        + q[(unsigned)node * 40u + (unsigned)(active ? lane : 0)])
                     : -__builtin_huge_valf();
    float m = v;
#pragma unroll
    for (int off = 32; off >= 1; off >>= 1) m = fmaxf(m, __shfl_xor(m, off));
    float e = active ? expf(v - m) : 0.0f;
    float ssum = e;
#pragma unroll
    for (int off = 32; off >= 1; off >>= 1) ssum += __shfl_xor(ssum, off);
    float ls = logf(ssum);
    if (active) out[(unsigned)node * 40u + (unsigned)lane] = v - m - ls;
}

extern "C" void kernel_launch(void* const* d_in, const int* in_sizes, int n_in,
                              void* d_out, int out_size, void* d_ws, size_t ws_size,
                              hipStream_t stream) {
    const float* x   = (const float*)d_in[0];
    const void*  ei  = d_in[1];
    const float* W1l = (const float*)d_in[2];
    const float* W1r = (const float*)d_in[3];
    const float* b1  = (const float*)d_in[4];
    const float* W2l = (const float*)d_in[5];
    const float* W2r = (const float*)d_in[6];
    const float* b2  = (const float*)d_in[7];
    float* out = (float*)d_out;

    const long long E = (long long)in_sizes[1] / 2;
    const int NPB = (int)((E + CHUNK - 1) / CHUNK);

    char* ws = (char*)d_ws;
    int*      flag      = (int*)ws;
    unsigned* bcount    = (unsigned*)(ws + 4096);
    unsigned* deg       = (unsigned*)(ws + 16384);
    float*    invc      = (float*)(ws + 416384);
    unsigned* row_start = (unsigned*)(ws + 816384);
    int*      csr       = (int*)(ws + 1216384);
    unsigned short* xb  = (unsigned short*)(ws + 14016384);
    unsigned short* aggb= (unsigned short*)(ws + 39616384);
    unsigned* slab      = (unsigned*)(ws + 39616384);        // alias (dead before aggb written)
    unsigned short* wp1 = (unsigned short*)(ws + 65216384);
    unsigned short* wp2 = (unsigned short*)(ws + 65281920);
    unsigned char*  pq  = (unsigned char*)(ws + 65310720);
    float*    q         = (float*)(ws + 69310720);
    unsigned char*  xq  = (unsigned char*)(ws + 90910720);

    // cast + pack_w + detect + bcount-zero in one horizontal launch
    prep_kernel<<<CAST_BLOCKS + 21 + 1, 256, 0, stream>>>(x, xb, xq, W1l, W1r, W2l, W2r,
                                                          wp1, wp2, (const int*)ei, flag, bcount);

    // CSR build: LDS counting-sort partition -> per-bucket build (with inline prefix)
    partition_kernel<<<NPB, 1024, 0, stream>>>(ei, flag, bcount, slab, E);
    build_kernel<<<NBUCK, 256, 0, stream>>>(slab, bcount, deg, invc, row_start, csr);

    // layer 1: fp8 gather-mean of x (two half-range launches), then fused GEMM1+GEMM2
    gather_fp8_kernel<<<12500, 256, 0, stream>>>(xq, csr, row_start, deg, invc, aggb, 0, 50000);
    gather_fp8_kernel<<<12500, 256, 0, stream>>>(xq, csr, row_start, deg, invc, aggb, 50000, 100000);
    gemm12_kernel<<<(N_NODES + 63) / 64, 256, 0, stream>>>(aggb, xb, wp1, b1, wp2, b2, pq, q);

    // layer 2 gather-mean + log_softmax
    gather40_kernel<<<(N_NODES + 3) / 4, 256, 0, stream>>>(pq, q, csr, row_start, deg, invc, out);
}

// Round 8
// 324.716 us; speedup vs baseline: 1.0115x; 1.0115x over previous
//
#include <hip/hip_runtime.h>
#include <hip/hip_bf16.h>
#include <hip/hip_fp8.h>
#include <math.h>

#define N_NODES 100000
#define D_IN    128
#define D_HID   128
#define D_OUT   40
#define NBUCK   391      // ceil(100000/256), bucket = dst >> 8
#define CHUNK   4096     // edges per partition block (1024 threads, 4 edges/thread)
#define SLABCAP 16320    // per-bucket slab capacity (mean 8184, sigma~90 -> no overflow)
#define CAST_BLOCKS 6250 // (100000*128/8)/256

// ---------------- workspace layout (bytes) ----------------
// flag      : 0          (4)
// bcount    : 4096       (1564)
// deg       : 16384      (400,000 u32)
// invc      : 416,384    (400,000 f32)
// row_start : 816,384    (400,000 u32)
// csr       : 1,216,384  (12,800,000 i32)             ends 14,016,384
// xb (bf16) : 14,016,384 (25,600,000)                 ends 39,616,384
// aggb(bf16): 39,616,384 (25,600,000)                 ends 65,216,384
//   alias before aggb written: slab (u32, NBUCK*16320*4 = 25,524,480) @39,616,384
// wp1 (bf16): 65,216,384 (65,536)                     ends 65,281,920
// wp2 (bf16): 65,281,920 (20,480)                     ends 65,302,400 (pad to 65,310,720)
// pq  (fp8) : 65,310,720 (4,000,000)                  ends 69,310,720
// q   (f32) : 69,310,720 (16,000,000)                 ends 85,310,720
// xq  (fp8) : 90,910,720 (12,800,000)                 ends 103,710,720

using short8  = __attribute__((ext_vector_type(8))) short;
using float4v = __attribute__((ext_vector_type(4))) float;
using floatx2 = __attribute__((ext_vector_type(2))) float;

__device__ __forceinline__ unsigned short f2b(float f) {
    __hip_bfloat16 b = __float2bfloat16(f);
    return *(unsigned short*)&b;
}
__device__ __forceinline__ unsigned packb(float a, float b) {
    return (unsigned)f2b(a) | ((unsigned)f2b(b) << 16);
}

__device__ __forceinline__ unsigned char f2q(float f) {
    __hip_fp8_e4m3 v(f);
    return *(unsigned char*)&v;
}
template <int SEL>
__device__ __forceinline__ float q2f(unsigned u) {
#if __has_builtin(__builtin_amdgcn_cvt_f32_fp8)
    return __builtin_amdgcn_cvt_f32_fp8((int)u, SEL);
#else
    unsigned char b = (u >> (SEL * 8)) & 0xff;
    __hip_fp8_e4m3 v;
    *(unsigned char*)&v = b;
    return (float)v;
#endif
}
// packed: convert 2 fp8 to float2 in one instr
template <bool HI>
__device__ __forceinline__ floatx2 pkcvt(unsigned u) {
#if __has_builtin(__builtin_amdgcn_cvt_pk_f32_fp8)
    return __builtin_amdgcn_cvt_pk_f32_fp8((int)u, HI);
#else
    floatx2 r;
    if constexpr (HI) { r[0] = q2f<2>(u); r[1] = q2f<3>(u); }
    else              { r[0] = q2f<0>(u); r[1] = q2f<1>(u); }
    return r;
#endif
}

__device__ __forceinline__ long long edge_at(const void* ei, int is64, long long idx) {
    if (is64) return ((const long long*)ei)[idx];
    return (long long)((const int*)ei)[idx];
}

// Horizontal fusion: cast (blocks 0..6249) | pack_w (6250..6270) | detect+zero (6271)
__global__ __launch_bounds__(256) void prep_kernel(const float* __restrict__ x,
                                                   unsigned short* __restrict__ xb,
                                                   unsigned char* __restrict__ xq,
                                                   const float* __restrict__ W1l,
                                                   const float* __restrict__ W1r,
                                                   const float* __restrict__ W2l,
                                                   const float* __restrict__ W2r,
                                                   unsigned short* __restrict__ wp1,
                                                   unsigned short* __restrict__ wp2,
                                                   const int* __restrict__ ei,
                                                   int* __restrict__ flag,
                                                   unsigned* __restrict__ bcount) {
    const int b = blockIdx.x;
    if (b < CAST_BLOCKS) {
        // ---- cast: x (f32 [N,128]) -> xb (bf16) + xq (fp8 e4m3)
        long long i = ((long long)b * 256 + threadIdx.x) * 8;
        if (i >= (long long)N_NODES * 128) return;
        float4 a = *(const float4*)&x[i];
        float4 c = *(const float4*)&x[i + 4];
        ushort4 o0, o1;
        o0.x = f2b(a.x); o0.y = f2b(a.y); o0.z = f2b(a.z); o0.w = f2b(a.w);
        o1.x = f2b(c.x); o1.y = f2b(c.y); o1.z = f2b(c.z); o1.w = f2b(c.w);
        *(ushort4*)&xb[i] = o0;
        *(ushort4*)&xb[i + 4] = o1;
        uint2 p;
        p.x = (unsigned)f2q(a.x) | ((unsigned)f2q(a.y) << 8)
            | ((unsigned)f2q(a.z) << 16) | ((unsigned)f2q(a.w) << 24);
        p.y = (unsigned)f2q(c.x) | ((unsigned)f2q(c.y) << 8)
            | ((unsigned)f2q(c.z) << 16) | ((unsigned)f2q(c.w) << 24);
        *(uint2*)&xq[i] = p;
    } else if (b < CAST_BLOCKS + 21) {
        // ---- pack weights into MFMA B-fragment order (bf16)
        int t = (b - CAST_BLOCKS) * 256 + threadIdx.x;
        if (t < 4096) {                     // wp1 entries (ct,ks,lane)
            int lane = t & 63;
            int ks = (t >> 6) & 7;
            int ct = t >> 9;
            int n = ct * 16 + (lane & 15);
            int kr = (lane >> 4) * 8;
            unsigned short v[8];
#pragma unroll
            for (int j = 0; j < 8; ++j) {
                int k = ks * 32 + kr + j;
                float f = (k < 128) ? W1l[k * 128 + n] : W1r[(k - 128) * 128 + n];
                v[j] = f2b(f);
            }
            ushort4 o0 = {v[0], v[1], v[2], v[3]};
            ushort4 o1 = {v[4], v[5], v[6], v[7]};
            *(ushort4*)&wp1[t * 8] = o0;
            *(ushort4*)&wp1[t * 8 + 4] = o1;
        } else if (t < 4096 + 1280) {       // wp2 entries
            int u = t - 4096;
            int lane = u & 63;
            int ks = (u >> 6) & 3;
            int ct = u >> 8;
            int n = ct * 16 + (lane & 15);
            int kr = (lane >> 4) * 8;
            unsigned short v[8];
#pragma unroll
            for (int j = 0; j < 8; ++j) {
                int k = ks * 32 + kr + j;
                float f = (n < 40) ? W2l[k * 40 + n] : W2r[k * 40 + (n - 40)];
                v[j] = f2b(f);
            }
            ushort4 o0 = {v[0], v[1], v[2], v[3]};
            ushort4 o1 = {v[4], v[5], v[6], v[7]};
            *(ushort4*)&wp2[u * 8] = o0;
            *(ushort4*)&wp2[u * 8 + 4] = o1;
        }
    } else {
        // ---- detect int64 vs int32 edge_index (wave-parallel) + zero bcount
        const int t = threadIdx.x;
        if (t < 64) {
            int ok = 1;
#pragma unroll
            for (int k = 0; k < 4; ++k) {
                if (ei[2 * (t * 4 + k) + 1] != 0) ok = 0;
            }
            int all0 = __all(ok);
            if (t == 0) *flag = all0 ? 1 : 0;
        }
        if (t < NBUCK) bcount[t] = 0u;
        if (t + 256 < NBUCK) bcount[t + 256] = 0u;
    }
}

// Block-level LDS counting sort, then coalesced slab writes.
// 1024 threads, CHUNK=4096 edges/block. Single-pass edge reads (registers);
// scan via wave-level shfl (2 barriers).
__global__ __launch_bounds__(1024) void partition_kernel(const void* __restrict__ ei,
                                                         const int* __restrict__ flag,
                                                         unsigned* __restrict__ bcount,
                                                         unsigned* __restrict__ slab,
                                                         long long E) {
    __shared__ unsigned hist[NBUCK];     // counts, then cursor
    __shared__ unsigned lstart[NBUCK];   // local exclusive offsets
    __shared__ unsigned gofs[NBUCK];     // b*SLABCAP + gbase - lstart[b]
    __shared__ unsigned s[512];
    __shared__ unsigned ws[16];
    __shared__ unsigned rec[CHUNK];
    __shared__ unsigned short bkt[CHUNK];

    const int tid = threadIdx.x;
    const int lane = tid & 63;
    const int w = tid >> 6;              // wave 0..15
    const int is64 = *flag;
    const long long cb = (long long)blockIdx.x * CHUNK;
    const unsigned n = (unsigned)(((E - cb) < (long long)CHUNK) ? (E - cb) : CHUNK);

    if (tid < NBUCK) hist[tid] = 0;
    __syncthreads();

    // pass 1: load edges ONCE into registers + histogram
    unsigned esrc[CHUNK / 1024], edst[CHUNK / 1024];
#pragma unroll
    for (int j = 0; j < CHUNK / 1024; ++j) {
        unsigned e = j * 1024 + tid;
        if (e < n) {
            esrc[j] = (unsigned)edge_at(ei, is64, cb + e);
            edst[j] = (unsigned)edge_at(ei, is64, E + cb + e);
            atomicAdd(&hist[edst[j] >> 8], 1u);
        }
    }
    __syncthreads();

    // inclusive scan of hist via wave shfl-scan + cross-wave fixup
    {
        unsigned v0 = (tid < NBUCK) ? hist[tid] : 0u;
        unsigned x = v0;
#pragma unroll
        for (int off = 1; off < 64; off <<= 1) {
            unsigned t = __shfl_up(x, off);
            if (lane >= off) x += t;
        }
        if (lane == 63) ws[w] = x;
        __syncthreads();
        if (w == 0) {
            unsigned y = (lane < 16) ? ws[lane] : 0u;
#pragma unroll
            for (int off = 1; off < 16; off <<= 1) {
                unsigned t = __shfl_up(y, off);
                if (lane >= off) y += t;
            }
            if (lane < 16) ws[lane] = y;
        }
        __syncthreads();
        unsigned pre = (w > 0) ? ws[w - 1] : 0u;
        if (tid < NBUCK) s[tid] = x + pre;   // inclusive scan
    }
    if (tid < NBUCK) {
        unsigned cnt = hist[tid];
        unsigned ex = s[tid] - cnt;
        lstart[tid] = ex;
        if (cnt) {
            unsigned g = atomicAdd(&bcount[tid], cnt);
            gofs[tid] = (unsigned)(tid * SLABCAP) + g - ex;
        }
        hist[tid] = 0;   // reuse as cursor
    }
    __syncthreads();

    // pass 2: scatter into LDS from registers, bucket-grouped
#pragma unroll
    for (int j = 0; j < CHUNK / 1024; ++j) {
        unsigned e = j * 1024 + tid;
        if (e < n) {
            unsigned d = edst[j];
            unsigned b = d >> 8;
            unsigned loc = atomicAdd(&hist[b], 1u);
            unsigned slot = lstart[b] + loc;
            rec[slot] = ((d & 255u) << 17) | esrc[j];
            bkt[slot] = (unsigned short)b;
        }
    }
    __syncthreads();

    // pass 3: coalesced global writes (consecutive slots -> consecutive slab addrs per run)
#pragma unroll
    for (int j = 0; j < CHUNK / 1024; ++j) {
        unsigned i = j * 1024 + tid;
        if (i < n) {
            unsigned b = bkt[i];
            slab[gofs[b] + i] = rec[i];
        }
    }
}

// Per-bucket fine CSR build in LDS (reads slab, writes csr at prefix offsets).
// Inline exclusive prefix of bcount; wave-level reductions/scans.
__global__ __launch_bounds__(256) void build_kernel(const unsigned* __restrict__ slab,
                                                    const unsigned* __restrict__ bcount,
                                                    unsigned* __restrict__ deg,
                                                    float* __restrict__ invc,
                                                    unsigned* __restrict__ row_start,
                                                    int* __restrict__ csr) {
    __shared__ unsigned red[4];
    __shared__ unsigned ws[4];
    __shared__ unsigned cnt[256];
    const int tid = threadIdx.x;
    const int lane = tid & 63;
    const int w = tid >> 6;              // wave 0..3
    const int nb = blockIdx.x << 8;
    const long long sb = (long long)blockIdx.x * SLABCAP;

    // exclusive prefix: es = sum of bcount[0..blockIdx.x)
    unsigned pv = 0;
    for (unsigned i = tid; i < (unsigned)blockIdx.x; i += 256) pv += bcount[i];
#pragma unroll
    for (int off = 32; off >= 1; off >>= 1) pv += __shfl_xor(pv, off);
    if (lane == 0) red[w] = pv;
    __syncthreads();
    const unsigned es = red[0] + red[1] + red[2] + red[3];
    const unsigned n  = bcount[blockIdx.x];

    cnt[tid] = 0;
    __syncthreads();
    for (unsigned i = tid; i < n; i += 256) {
        unsigned d = slab[sb + i] >> 17;
        atomicAdd(&cnt[d], 1u);
    }
    __syncthreads();
    unsigned v = cnt[tid];
    // inclusive wave scan + cross-wave fixup
    unsigned x = v;
#pragma unroll
    for (int off = 1; off < 64; off <<= 1) {
        unsigned t = __shfl_up(x, off);
        if (lane >= off) x += t;
    }
    if (lane == 63) ws[w] = x;
    __syncthreads();
    unsigned pre = 0;
#pragma unroll
    for (int k = 0; k < 4; ++k) if (k < w) pre += ws[k];
    unsigned ex = x + pre - v;
    int node = nb + tid;
    if (node < N_NODES) {
        deg[node] = v;
        invc[node] = 1.0f / fmaxf((float)v, 1.0f);
        row_start[node] = es + ex;
    }
    __syncthreads();
    cnt[tid] = ex;   // reuse as cursor
    __syncthreads();
    for (unsigned i = tid; i < n; i += 256) {
        unsigned pr = slab[sb + i];
        unsigned d = pr >> 17;
        unsigned pos = es + atomicAdd(&cnt[d], 1u);
        csr[pos] = (int)(pr & 0x1FFFFu);
    }
}

// Gather-mean over 128 fp8 cols -> bf16 agg: one wave per node.
// Lane = (slot s = lane>>4, colgroup cg = lane&15): lane loads uint2 (8 fp8 cols) of
// neighbor j+s -> 4 neighbors per wave-load; packed cvt+add (2 elems/instr).
// Launched twice over half node-ranges (keeps each dispatch below middle kernels
// in the rocprof top-5 so middle kernels become visible).
__global__ __launch_bounds__(256) void gather_fp8_kernel(const unsigned char* __restrict__ featq,
                                                         const int* __restrict__ csr,
                                                         const unsigned* __restrict__ row_start,
                                                         const unsigned* __restrict__ deg,
                                                         const float* __restrict__ invc,
                                                         unsigned short* __restrict__ aggb,
                                                         int node0, int nend) {
    const int wave = threadIdx.x >> 6;
    const int lane = threadIdx.x & 63;
    const int node = node0 + blockIdx.x * 4 + wave;
    if (node >= nend) return;

    const unsigned start = row_start[node];
    const unsigned cnt = deg[node];
    const int s = lane >> 4;              // slot 0..3
    const unsigned cgo = (unsigned)((lane & 15) * 8);   // col-group byte offset

    floatx2 acc[4];
#pragma unroll
    for (int k = 0; k < 4; ++k) acc[k] = (floatx2){0.f, 0.f};

    for (unsigned base = 0; base < cnt; base += 64) {
        unsigned rem = cnt - base;
        if (rem > 64u) rem = 64u;
        int nid = (lane < (int)rem) ? csr[start + base + lane] : 0;
        for (unsigned j = 0; j < rem; j += 8) {
            uint2 u0 = {0u, 0u}, u1 = {0u, 0u};
            unsigned i0 = j + s;
            unsigned i1 = j + 4 + s;
            int s0 = __shfl(nid, (int)(i0 & 63));
            int s1 = __shfl(nid, (int)(i1 & 63));
            if (i0 < rem) u0 = *(const uint2*)&featq[((unsigned)s0 << 7) + cgo];
            if (i1 < rem) u1 = *(const uint2*)&featq[((unsigned)s1 << 7) + cgo];
            acc[0] += pkcvt<false>(u0.x); acc[1] += pkcvt<true>(u0.x);
            acc[2] += pkcvt<false>(u0.y); acc[3] += pkcvt<true>(u0.y);
            acc[0] += pkcvt<false>(u1.x); acc[1] += pkcvt<true>(u1.x);
            acc[2] += pkcvt<false>(u1.y); acc[3] += pkcvt<true>(u1.y);
        }
    }

    // reduce across the 4 slots (lanes differing in bits 4,5)
#pragma unroll
    for (int k = 0; k < 4; ++k) {
        acc[k][0] += __shfl_xor(acc[k][0], 16);
        acc[k][1] += __shfl_xor(acc[k][1], 16);
        acc[k][0] += __shfl_xor(acc[k][0], 32);
        acc[k][1] += __shfl_xor(acc[k][1], 32);
    }

    if (lane < 16) {
        const float ic = invc[node];
        uint4 o;
        o.x = packb(acc[0][0] * ic, acc[0][1] * ic);
        o.y = packb(acc[1][0] * ic, acc[1][1] * ic);
        o.z = packb(acc[2][0] * ic, acc[2][1] * ic);
        o.w = packb(acc[3][0] * ic, acc[3][1] * ic);
        *(uint4*)&aggb[(unsigned)node * 128u + cgo] = o;
    }
}

// Fused layer-1 GEMM + layer-2 projection: h = relu([aggb|xb]@wp1 + b1) stays in LDS,
// then [pq|q] = h@wp2 (+b2 on q half). 64 rows/block, 4 waves.
__global__ __launch_bounds__(256) void gemm12_kernel(const unsigned short* __restrict__ aggb,
                                                     const unsigned short* __restrict__ xb,
                                                     const unsigned short* __restrict__ wp1,
                                                     const float* __restrict__ b1,
                                                     const unsigned short* __restrict__ wp2,
                                                     const float* __restrict__ b2,
                                                     unsigned char* __restrict__ pq,
                                                     float* __restrict__ q) {
    __shared__ unsigned short sh[64][136];   // h rows (bf16), stride 272B (16B-aligned)
    const int wave = threadIdx.x >> 6;
    const int lane = threadIdx.x & 63;
    const int row0 = blockIdx.x * 64 + wave * 16;
    const unsigned abase = (unsigned)(row0 + (lane & 15)) * 128u + (unsigned)((lane >> 4) * 8);

    // ---- phase 1: h-strip via MFMA
    float4v acc[8];
#pragma unroll
    for (int ct = 0; ct < 8; ++ct) acc[ct] = (float4v){0.f, 0.f, 0.f, 0.f};

#pragma unroll
    for (int ks = 0; ks < 8; ++ks) {
        union { uint4 u; short8 s; } af;
        if (ks < 4) af.u = *(const uint4*)&aggb[abase + ks * 32];
        else        af.u = *(const uint4*)&xb[abase + (ks - 4) * 32];
#pragma unroll
        for (int ct = 0; ct < 8; ++ct) {
            union { uint4 u; short8 s; } bf;
            bf.u = *(const uint4*)&wp1[((ct * 8 + ks) * 64 + lane) * 8];
            acc[ct] = __builtin_amdgcn_mfma_f32_16x16x32_bf16(af.s, bf.s, acc[ct], 0, 0, 0);
        }
    }

    // relu+bias -> LDS (local rows of this wave's strip; no cross-wave sharing)
    const int lrow0 = wave * 16 + (lane >> 4) * 4;
    const int ccol = lane & 15;
#pragma unroll
    for (int ct = 0; ct < 8; ++ct) {
        const int col = ct * 16 + ccol;
        const float bv = b1[col];
#pragma unroll
        for (int r = 0; r < 4; ++r)
            sh[lrow0 + r][col] = f2b(fmaxf(acc[ct][r] + bv, 0.0f));
    }
    // wave-synchronous: each wave reads only rows it wrote; no __syncthreads needed.

    // ---- phase 2: [pq|q] strip via MFMA from LDS
    const unsigned short* aptr = &sh[wave * 16 + (lane & 15)][(lane >> 4) * 8];

    float4v acc2[5];
#pragma unroll
    for (int ct = 0; ct < 5; ++ct) acc2[ct] = (float4v){0.f, 0.f, 0.f, 0.f};

#pragma unroll
    for (int ks = 0; ks < 4; ++ks) {
        union { uint4 u; short8 s; } af;
        af.u = *(const uint4*)&aptr[ks * 32];
#pragma unroll
        for (int ct = 0; ct < 5; ++ct) {
            union { uint4 u; short8 s; } bf;
            bf.u = *(const uint4*)&wp2[((ct * 4 + ks) * 64 + lane) * 8];
            acc2[ct] = __builtin_amdgcn_mfma_f32_16x16x32_bf16(af.s, bf.s, acc2[ct], 0, 0, 0);
        }
    }

    const int crow0 = row0 + (lane >> 4) * 4;
#pragma unroll
    for (int ct = 0; ct < 5; ++ct) {
        const int col = ct * 16 + ccol;        // 0..79
#pragma unroll
        for (int r = 0; r < 4; ++r) {
            int row = crow0 + r;
            if (row < N_NODES) {
                if (col < D_OUT) {
                    pq[(unsigned)row * 40u + (unsigned)col] = f2q(acc2[ct][r]);
                } else {
                    q[(unsigned)row * 40u + (unsigned)(col - D_OUT)] = acc2[ct][r] + b2[col - D_OUT];
                }
            }
        }
    }
}

// out = log_softmax(meanagg(pq) + q): one wave per node.
// Lane = (slot s = lane/10, colgroup cg = lane%10): lane loads uint (4 fp8 cols) of
// neighbor j+s -> 6 neighbors per load instr; 4-deep unroll (24 neighbors/iter,
// measured faster than 3-deep). Launched twice over half node-ranges (visibility).
__global__ __launch_bounds__(256) void gather40_kernel(const unsigned char* __restrict__ pq,
                                                       const float* __restrict__ q,
                                                       const int* __restrict__ csr,
                                                       const unsigned* __restrict__ row_start,
                                                       const unsigned* __restrict__ deg,
                                                       const float* __restrict__ invc,
                                                       float* __restrict__ out,
                                                       int node0, int nend) {
    __shared__ float sm[4][40];
    const int wave = threadIdx.x >> 6;
    const int lane = threadIdx.x & 63;
    const int node = node0 + blockIdx.x * 4 + wave;
    if (node >= nend) return;

    const unsigned start = row_start[node];
    const unsigned cnt = deg[node];
    const int s = lane / 10;          // 0..6 (6 -> idle)
    const int cg = lane % 10;         // col group (4 cols)
    const unsigned cgo = (unsigned)(cg * 4);
    const bool gactive = s < 6;

    floatx2 a01 = (floatx2){0.f, 0.f}, a23 = (floatx2){0.f, 0.f};

    for (unsigned base = 0; base < cnt; base += 64) {
        unsigned rem = cnt - base;
        if (rem > 64u) rem = 64u;
        int nid = (lane < (int)rem) ? csr[start + base + lane] : 0;
        for (unsigned j = 0; j < rem; j += 24) {
            unsigned u[4];
#pragma unroll
            for (int t = 0; t < 4; ++t) {
                unsigned idx = j + t * 6 + s;
                int sid = __shfl(nid, (int)(idx & 63));
                bool valid = gactive && (idx < rem);
                u[t] = valid ? *(const unsigned*)&pq[(unsigned)sid * 40u + cgo] : 0u;
            }
#pragma unroll
            for (int t = 0; t < 4; ++t) {
                a01 += pkcvt<false>(u[t]);
                a23 += pkcvt<true>(u[t]);
            }
        }
    }

    float a0 = a01[0], a1 = a01[1], a2 = a23[0], a3 = a23[1];
    // reduce slots 0..5 into slot 0 (lanes 0..9), guarded to avoid pollution
    {
        float t0, t1, t2, t3;
        t0 = __shfl(a0, lane + 30); t1 = __shfl(a1, lane + 30);
        t2 = __shfl(a2, lane + 30); t3 = __shfl(a3, lane + 30);
        if (lane < 30) { a0 += t0; a1 += t1; a2 += t2; a3 += t3; }
        t0 = __shfl(a0, lane + 20); t1 = __shfl(a1, lane + 20);
        t2 = __shfl(a2, lane + 20); t3 = __shfl(a3, lane + 20);
        if (lane < 10) { a0 += t0; a1 += t1; a2 += t2; a3 += t3; }
        t0 = __shfl(a0, lane + 10); t1 = __shfl(a1, lane + 10);
        t2 = __shfl(a2, lane + 10); t3 = __shfl(a3, lane + 10);
        if (lane < 10) { a0 += t0; a1 += t1; a2 += t2; a3 += t3; }
    }
    if (lane < 10) {
        sm[wave][cg * 4 + 0] = a0;
        sm[wave][cg * 4 + 1] = a1;
        sm[wave][cg * 4 + 2] = a2;
        sm[wave][cg * 4 + 3] = a3;
    }
    // wave-synchronous LDS round-trip (no barrier needed within a wave)
    const bool active = lane < D_OUT;
    float v = active ? (sm[wave][active ? lane : 0] * invc[node]
                        + q[(unsigned)node * 40u + (unsigned)(active ? lane : 0)])
                     : -__builtin_huge_valf();
    float m = v;
#pragma unroll
    for (int off = 32; off >= 1; off >>= 1) m = fmaxf(m, __shfl_xor(m, off));
    float e = active ? expf(v - m) : 0.0f;
    float ssum = e;
#pragma unroll
    for (int off = 32; off >= 1; off >>= 1) ssum += __shfl_xor(ssum, off);
    float ls = logf(ssum);
    if (active) out[(unsigned)node * 40u + (unsigned)lane] = v - m - ls;
}

extern "C" void kernel_launch(void* const* d_in, const int* in_sizes, int n_in,
                              void* d_out, int out_size, void* d_ws, size_t ws_size,
                              hipStream_t stream) {
    const float* x   = (const float*)d_in[0];
    const void*  ei  = d_in[1];
    const float* W1l = (const float*)d_in[2];
    const float* W1r = (const float*)d_in[3];
    const float* b1  = (const float*)d_in[4];
    const float* W2l = (const float*)d_in[5];
    const float* W2r = (const float*)d_in[6];
    const float* b2  = (const float*)d_in[7];
    float* out = (float*)d_out;

    const long long E = (long long)in_sizes[1] / 2;
    const int NPB = (int)((E + CHUNK - 1) / CHUNK);

    char* ws = (char*)d_ws;
    int*      flag      = (int*)ws;
    unsigned* bcount    = (unsigned*)(ws + 4096);
    unsigned* deg       = (unsigned*)(ws + 16384);
    float*    invc      = (float*)(ws + 416384);
    unsigned* row_start = (unsigned*)(ws + 816384);
    int*      csr       = (int*)(ws + 1216384);
    unsigned short* xb  = (unsigned short*)(ws + 14016384);
    unsigned short* aggb= (unsigned short*)(ws + 39616384);
    unsigned* slab      = (unsigned*)(ws + 39616384);        // alias (dead before aggb written)
    unsigned short* wp1 = (unsigned short*)(ws + 65216384);
    unsigned short* wp2 = (unsigned short*)(ws + 65281920);
    unsigned char*  pq  = (unsigned char*)(ws + 65310720);
    float*    q         = (float*)(ws + 69310720);
    unsigned char*  xq  = (unsigned char*)(ws + 90910720);

    // cast + pack_w + detect + bcount-zero in one horizontal launch
    prep_kernel<<<CAST_BLOCKS + 21 + 1, 256, 0, stream>>>(x, xb, xq, W1l, W1r, W2l, W2r,
                                                          wp1, wp2, (const int*)ei, flag, bcount);

    // CSR build: LDS counting-sort partition (single-pass edge reads) -> per-bucket build
    partition_kernel<<<NPB, 1024, 0, stream>>>(ei, flag, bcount, slab, E);
    build_kernel<<<NBUCK, 256, 0, stream>>>(slab, bcount, deg, invc, row_start, csr);

    // layer 1: fp8 gather-mean of x (two half-range launches), then fused GEMM1+GEMM2
    gather_fp8_kernel<<<12500, 256, 0, stream>>>(xq, csr, row_start, deg, invc, aggb, 0, 50000);
    gather_fp8_kernel<<<12500, 256, 0, stream>>>(xq, csr, row_start, deg, invc, aggb, 50000, 100000);
    gemm12_kernel<<<(N_NODES + 63) / 64, 256, 0, stream>>>(aggb, xb, wp1, b1, wp2, b2, pq, q);

    // layer 2 gather-mean + log_softmax (two half-range launches)
    gather40_kernel<<<12500, 256, 0, stream>>>(pq, q, csr, row_start, deg, invc, out, 0, 50000);
    gather40_kernel<<<12500, 256, 0, stream>>>(pq, q, csr, row_start, deg, invc, out, 50000, 100000);
}

// Round 9
// 308.296 us; speedup vs baseline: 1.0654x; 1.0533x over previous
//
#include <hip/hip_runtime.h>
#include <hip/hip_bf16.h>
#include <hip/hip_fp8.h>
#include <math.h>

#define N_NODES 100000
#define D_IN    128
#define D_HID   128
#define D_OUT   40
#define NBUCK   391      // ceil(100000/256), bucket = dst >> 8
#define CHUNK   8192     // edges per partition block (1024 threads, 8 edges/thread)
#define SLABCAP 16320    // per-bucket slab capacity (mean 8184, sigma~90 -> no overflow)
#define CAST_BLOCKS 6250 // (100000*128/8)/256

// ---------------- workspace layout (bytes) ----------------
// flag      : 0          (4)
// bcount    : 4096       (1564)
// deg       : 16384      (400,000 u32)
// invc      : 416,384    (400,000 f32)
// row_start : 816,384    (400,000 u32)
// csr       : 1,216,384  (12,800,000 i32)             ends 14,016,384
// xb (bf16) : 14,016,384 (25,600,000)                 ends 39,616,384
// aggb(bf16): 39,616,384 (25,600,000)                 ends 65,216,384
//   alias before aggb written: slab (u32, NBUCK*16320*4 = 25,524,480) @39,616,384
// wp1 (bf16): 65,216,384 (65,536)                     ends 65,281,920
// wp2 (bf16): 65,281,920 (20,480)                     ends 65,302,400 (pad to 65,310,720)
// pq  (fp8) : 65,310,720 (4,000,000)                  ends 69,310,720
// q   (f32) : 69,310,720 (16,000,000)                 ends 85,310,720
// xq  (fp8) : 90,910,720 (12,800,000)                 ends 103,710,720

using short8  = __attribute__((ext_vector_type(8))) short;
using float4v = __attribute__((ext_vector_type(4))) float;
using floatx2 = __attribute__((ext_vector_type(2))) float;

__device__ __forceinline__ unsigned short f2b(float f) {
    __hip_bfloat16 b = __float2bfloat16(f);
    return *(unsigned short*)&b;
}
__device__ __forceinline__ unsigned packb(float a, float b) {
    return (unsigned)f2b(a) | ((unsigned)f2b(b) << 16);
}

__device__ __forceinline__ unsigned char f2q(float f) {
    __hip_fp8_e4m3 v(f);
    return *(unsigned char*)&v;
}
template <int SEL>
__device__ __forceinline__ float q2f(unsigned u) {
#if __has_builtin(__builtin_amdgcn_cvt_f32_fp8)
    return __builtin_amdgcn_cvt_f32_fp8((int)u, SEL);
#else
    unsigned char b = (u >> (SEL * 8)) & 0xff;
    __hip_fp8_e4m3 v;
    *(unsigned char*)&v = b;
    return (float)v;
#endif
}
// packed: convert 2 fp8 to float2 in one instr
template <bool HI>
__device__ __forceinline__ floatx2 pkcvt(unsigned u) {
#if __has_builtin(__builtin_amdgcn_cvt_pk_f32_fp8)
    return __builtin_amdgcn_cvt_pk_f32_fp8((int)u, HI);
#else
    floatx2 r;
    if constexpr (HI) { r[0] = q2f<2>(u); r[1] = q2f<3>(u); }
    else              { r[0] = q2f<0>(u); r[1] = q2f<1>(u); }
    return r;
#endif
}

__device__ __forceinline__ long long edge_at(const void* ei, int is64, long long idx) {
    if (is64) return ((const long long*)ei)[idx];
    return (long long)((const int*)ei)[idx];
}

// Horizontal fusion: cast (blocks 0..6249) | pack_w (6250..6270) | detect+zero (6271)
__global__ __launch_bounds__(256) void prep_kernel(const float* __restrict__ x,
                                                   unsigned short* __restrict__ xb,
                                                   unsigned char* __restrict__ xq,
                                                   const float* __restrict__ W1l,
                                                   const float* __restrict__ W1r,
                                                   const float* __restrict__ W2l,
                                                   const float* __restrict__ W2r,
                                                   unsigned short* __restrict__ wp1,
                                                   unsigned short* __restrict__ wp2,
                                                   const int* __restrict__ ei,
                                                   int* __restrict__ flag,
                                                   unsigned* __restrict__ bcount) {
    const int b = blockIdx.x;
    if (b < CAST_BLOCKS) {
        // ---- cast: x (f32 [N,128]) -> xb (bf16) + xq (fp8 e4m3)
        long long i = ((long long)b * 256 + threadIdx.x) * 8;
        if (i >= (long long)N_NODES * 128) return;
        float4 a = *(const float4*)&x[i];
        float4 c = *(const float4*)&x[i + 4];
        ushort4 o0, o1;
        o0.x = f2b(a.x); o0.y = f2b(a.y); o0.z = f2b(a.z); o0.w = f2b(a.w);
        o1.x = f2b(c.x); o1.y = f2b(c.y); o1.z = f2b(c.z); o1.w = f2b(c.w);
        *(ushort4*)&xb[i] = o0;
        *(ushort4*)&xb[i + 4] = o1;
        uint2 p;
        p.x = (unsigned)f2q(a.x) | ((unsigned)f2q(a.y) << 8)
            | ((unsigned)f2q(a.z) << 16) | ((unsigned)f2q(a.w) << 24);
        p.y = (unsigned)f2q(c.x) | ((unsigned)f2q(c.y) << 8)
            | ((unsigned)f2q(c.z) << 16) | ((unsigned)f2q(c.w) << 24);
        *(uint2*)&xq[i] = p;
    } else if (b < CAST_BLOCKS + 21) {
        // ---- pack weights into MFMA B-fragment order (bf16)
        int t = (b - CAST_BLOCKS) * 256 + threadIdx.x;
        if (t < 4096) {                     // wp1 entries (ct,ks,lane)
            int lane = t & 63;
            int ks = (t >> 6) & 7;
            int ct = t >> 9;
            int n = ct * 16 + (lane & 15);
            int kr = (lane >> 4) * 8;
            unsigned short v[8];
#pragma unroll
            for (int j = 0; j < 8; ++j) {
                int k = ks * 32 + kr + j;
                float f = (k < 128) ? W1l[k * 128 + n] : W1r[(k - 128) * 128 + n];
                v[j] = f2b(f);
            }
            ushort4 o0 = {v[0], v[1], v[2], v[3]};
            ushort4 o1 = {v[4], v[5], v[6], v[7]};
            *(ushort4*)&wp1[t * 8] = o0;
            *(ushort4*)&wp1[t * 8 + 4] = o1;
        } else if (t < 4096 + 1280) {       // wp2 entries
            int u = t - 4096;
            int lane = u & 63;
            int ks = (u >> 6) & 3;
            int ct = u >> 8;
            int n = ct * 16 + (lane & 15);
            int kr = (lane >> 4) * 8;
            unsigned short v[8];
#pragma unroll
            for (int j = 0; j < 8; ++j) {
                int k = ks * 32 + kr + j;
                float f = (n < 40) ? W2l[k * 40 + n] : W2r[k * 40 + (n - 40)];
                v[j] = f2b(f);
            }
            ushort4 o0 = {v[0], v[1], v[2], v[3]};
            ushort4 o1 = {v[4], v[5], v[6], v[7]};
            *(ushort4*)&wp2[u * 8] = o0;
            *(ushort4*)&wp2[u * 8 + 4] = o1;
        }
    } else {
        // ---- detect int64 vs int32 edge_index (wave-parallel) + zero bcount
        const int t = threadIdx.x;
        if (t < 64) {
            int ok = 1;
#pragma unroll
            for (int k = 0; k < 4; ++k) {
                if (ei[2 * (t * 4 + k) + 1] != 0) ok = 0;
            }
            int all0 = __all(ok);
            if (t == 0) *flag = all0 ? 1 : 0;
        }
        if (t < NBUCK) bcount[t] = 0u;
        if (t + 256 < NBUCK) bcount[t + 256] = 0u;
    }
}

// Block-level LDS counting sort, then coalesced slab writes.
// 1024 threads, CHUNK=8192 edges/block (8 regs/thread; halves per-block scan overhead).
__global__ __launch_bounds__(1024) void partition_kernel(const void* __restrict__ ei,
                                                         const int* __restrict__ flag,
                                                         unsigned* __restrict__ bcount,
                                                         unsigned* __restrict__ slab,
                                                         long long E) {
    __shared__ unsigned hist[NBUCK];     // counts, then cursor
    __shared__ unsigned lstart[NBUCK];   // local exclusive offsets
    __shared__ unsigned gofs[NBUCK];     // b*SLABCAP + gbase - lstart[b]
    __shared__ unsigned s[512];
    __shared__ unsigned ws[16];
    __shared__ unsigned rec[CHUNK];
    __shared__ unsigned short bkt[CHUNK];

    const int tid = threadIdx.x;
    const int lane = tid & 63;
    const int w = tid >> 6;              // wave 0..15
    const int is64 = *flag;
    const long long cb = (long long)blockIdx.x * CHUNK;
    const unsigned n = (unsigned)(((E - cb) < (long long)CHUNK) ? (E - cb) : CHUNK);

    if (tid < NBUCK) hist[tid] = 0;
    __syncthreads();

    // pass 1: load edges ONCE into registers + histogram
    unsigned esrc[CHUNK / 1024], edst[CHUNK / 1024];
#pragma unroll
    for (int j = 0; j < CHUNK / 1024; ++j) {
        unsigned e = j * 1024 + tid;
        if (e < n) {
            esrc[j] = (unsigned)edge_at(ei, is64, cb + e);
            edst[j] = (unsigned)edge_at(ei, is64, E + cb + e);
            atomicAdd(&hist[edst[j] >> 8], 1u);
        }
    }
    __syncthreads();

    // inclusive scan of hist via wave shfl-scan + cross-wave fixup
    {
        unsigned v0 = (tid < NBUCK) ? hist[tid] : 0u;
        unsigned x = v0;
#pragma unroll
        for (int off = 1; off < 64; off <<= 1) {
            unsigned t = __shfl_up(x, off);
            if (lane >= off) x += t;
        }
        if (lane == 63) ws[w] = x;
        __syncthreads();
        if (w == 0) {
            unsigned y = (lane < 16) ? ws[lane] : 0u;
#pragma unroll
            for (int off = 1; off < 16; off <<= 1) {
                unsigned t = __shfl_up(y, off);
                if (lane >= off) y += t;
            }
            if (lane < 16) ws[lane] = y;
        }
        __syncthreads();
        unsigned pre = (w > 0) ? ws[w - 1] : 0u;
        if (tid < NBUCK) s[tid] = x + pre;   // inclusive scan
    }
    if (tid < NBUCK) {
        unsigned cnt = hist[tid];
        unsigned ex = s[tid] - cnt;
        lstart[tid] = ex;
        if (cnt) {
            unsigned g = atomicAdd(&bcount[tid], cnt);
            gofs[tid] = (unsigned)(tid * SLABCAP) + g - ex;
        }
        hist[tid] = 0;   // reuse as cursor
    }
    __syncthreads();

    // pass 2: scatter into LDS from registers, bucket-grouped
#pragma unroll
    for (int j = 0; j < CHUNK / 1024; ++j) {
        unsigned e = j * 1024 + tid;
        if (e < n) {
            unsigned d = edst[j];
            unsigned b = d >> 8;
            unsigned loc = atomicAdd(&hist[b], 1u);
            unsigned slot = lstart[b] + loc;
            rec[slot] = ((d & 255u) << 17) | esrc[j];
            bkt[slot] = (unsigned short)b;
        }
    }
    __syncthreads();

    // pass 3: coalesced global writes (consecutive slots -> consecutive slab addrs per run)
#pragma unroll
    for (int j = 0; j < CHUNK / 1024; ++j) {
        unsigned i = j * 1024 + tid;
        if (i < n) {
            unsigned b = bkt[i];
            slab[gofs[b] + i] = rec[i];
        }
    }
}

// Per-bucket fine CSR build in LDS (reads slab, writes csr at prefix offsets).
// Inline exclusive prefix of bcount; wave-level reductions/scans.
__global__ __launch_bounds__(256) void build_kernel(const unsigned* __restrict__ slab,
                                                    const unsigned* __restrict__ bcount,
                                                    unsigned* __restrict__ deg,
                                                    float* __restrict__ invc,
                                                    unsigned* __restrict__ row_start,
                                                    int* __restrict__ csr) {
    __shared__ unsigned red[4];
    __shared__ unsigned ws[4];
    __shared__ unsigned cnt[256];
    const int tid = threadIdx.x;
    const int lane = tid & 63;
    const int w = tid >> 6;              // wave 0..3
    const int nb = blockIdx.x << 8;
    const long long sb = (long long)blockIdx.x * SLABCAP;

    // exclusive prefix: es = sum of bcount[0..blockIdx.x)
    unsigned pv = 0;
    for (unsigned i = tid; i < (unsigned)blockIdx.x; i += 256) pv += bcount[i];
#pragma unroll
    for (int off = 32; off >= 1; off >>= 1) pv += __shfl_xor(pv, off);
    if (lane == 0) red[w] = pv;
    __syncthreads();
    const unsigned es = red[0] + red[1] + red[2] + red[3];
    const unsigned n  = bcount[blockIdx.x];

    cnt[tid] = 0;
    __syncthreads();
    for (unsigned i = tid; i < n; i += 256) {
        unsigned d = slab[sb + i] >> 17;
        atomicAdd(&cnt[d], 1u);
    }
    __syncthreads();
    unsigned v = cnt[tid];
    // inclusive wave scan + cross-wave fixup
    unsigned x = v;
#pragma unroll
    for (int off = 1; off < 64; off <<= 1) {
        unsigned t = __shfl_up(x, off);
        if (lane >= off) x += t;
    }
    if (lane == 63) ws[w] = x;
    __syncthreads();
    unsigned pre = 0;
#pragma unroll
    for (int k = 0; k < 4; ++k) if (k < w) pre += ws[k];
    unsigned ex = x + pre - v;
    int node = nb + tid;
    if (node < N_NODES) {
        deg[node] = v;
        invc[node] = 1.0f / fmaxf((float)v, 1.0f);
        row_start[node] = es + ex;
    }
    __syncthreads();
    cnt[tid] = ex;   // reuse as cursor
    __syncthreads();
    for (unsigned i = tid; i < n; i += 256) {
        unsigned pr = slab[sb + i];
        unsigned d = pr >> 17;
        unsigned pos = es + atomicAdd(&cnt[d], 1u);
        csr[pos] = (int)(pr & 0x1FFFFu);
    }
}

// Gather-mean over 128 fp8 cols -> bf16 agg: one wave per node.
// Lane = (slot s = lane>>4, colgroup cg = lane&15): lane loads uint2 (8 fp8 cols) of
// neighbor j+s -> 4 neighbors per wave-load; packed cvt+add (2 elems/instr).
__global__ __launch_bounds__(256) void gather_fp8_kernel(const unsigned char* __restrict__ featq,
                                                         const int* __restrict__ csr,
                                                         const unsigned* __restrict__ row_start,
                                                         const unsigned* __restrict__ deg,
                                                         const float* __restrict__ invc,
                                                         unsigned short* __restrict__ aggb) {
    const int wave = threadIdx.x >> 6;
    const int lane = threadIdx.x & 63;
    const int node = blockIdx.x * 4 + wave;
    if (node >= N_NODES) return;

    const unsigned start = row_start[node];
    const unsigned cnt = deg[node];
    const int s = lane >> 4;              // slot 0..3
    const unsigned cgo = (unsigned)((lane & 15) * 8);   // col-group byte offset

    floatx2 acc[4];
#pragma unroll
    for (int k = 0; k < 4; ++k) acc[k] = (floatx2){0.f, 0.f};

    for (unsigned base = 0; base < cnt; base += 64) {
        unsigned rem = cnt - base;
        if (rem > 64u) rem = 64u;
        int nid = (lane < (int)rem) ? csr[start + base + lane] : 0;
        for (unsigned j = 0; j < rem; j += 8) {
            uint2 u0 = {0u, 0u}, u1 = {0u, 0u};
            unsigned i0 = j + s;
            unsigned i1 = j + 4 + s;
            int s0 = __shfl(nid, (int)(i0 & 63));
            int s1 = __shfl(nid, (int)(i1 & 63));
            if (i0 < rem) u0 = *(const uint2*)&featq[((unsigned)s0 << 7) + cgo];
            if (i1 < rem) u1 = *(const uint2*)&featq[((unsigned)s1 << 7) + cgo];
            acc[0] += pkcvt<false>(u0.x); acc[1] += pkcvt<true>(u0.x);
            acc[2] += pkcvt<false>(u0.y); acc[3] += pkcvt<true>(u0.y);
            acc[0] += pkcvt<false>(u1.x); acc[1] += pkcvt<true>(u1.x);
            acc[2] += pkcvt<false>(u1.y); acc[3] += pkcvt<true>(u1.y);
        }
    }

    // reduce across the 4 slots (lanes differing in bits 4,5)
#pragma unroll
    for (int k = 0; k < 4; ++k) {
        acc[k][0] += __shfl_xor(acc[k][0], 16);
        acc[k][1] += __shfl_xor(acc[k][1], 16);
        acc[k][0] += __shfl_xor(acc[k][0], 32);
        acc[k][1] += __shfl_xor(acc[k][1], 32);
    }

    if (lane < 16) {
        const float ic = invc[node];
        uint4 o;
        o.x = packb(acc[0][0] * ic, acc[0][1] * ic);
        o.y = packb(acc[1][0] * ic, acc[1][1] * ic);
        o.z = packb(acc[2][0] * ic, acc[2][1] * ic);
        o.w = packb(acc[3][0] * ic, acc[3][1] * ic);
        *(uint4*)&aggb[(unsigned)node * 128u + cgo] = o;
    }
}

// Fused layer-1 GEMM + layer-2 projection: h = relu([aggb|xb]@wp1 + b1) stays in LDS,
// then [pq|q] = h@wp2 (+b2 on q half). 64 rows/block, 4 waves.
__global__ __launch_bounds__(256) void gemm12_kernel(const unsigned short* __restrict__ aggb,
                                                     const unsigned short* __restrict__ xb,
                                                     const unsigned short* __restrict__ wp1,
                                                     const float* __restrict__ b1,
                                                     const unsigned short* __restrict__ wp2,
                                                     const float* __restrict__ b2,
                                                     unsigned char* __restrict__ pq,
                                                     float* __restrict__ q) {
    __shared__ unsigned short sh[64][136];   // h rows (bf16), stride 272B (16B-aligned)
    const int wave = threadIdx.x >> 6;
    const int lane = threadIdx.x & 63;
    const int row0 = blockIdx.x * 64 + wave * 16;
    const unsigned abase = (unsigned)(row0 + (lane & 15)) * 128u + (unsigned)((lane >> 4) * 8);

    // ---- phase 1: h-strip via MFMA
    float4v acc[8];
#pragma unroll
    for (int ct = 0; ct < 8; ++ct) acc[ct] = (float4v){0.f, 0.f, 0.f, 0.f};

#pragma unroll
    for (int ks = 0; ks < 8; ++ks) {
        union { uint4 u; short8 s; } af;
        if (ks < 4) af.u = *(const uint4*)&aggb[abase + ks * 32];
        else        af.u = *(const uint4*)&xb[abase + (ks - 4) * 32];
#pragma unroll
        for (int ct = 0; ct < 8; ++ct) {
            union { uint4 u; short8 s; } bf;
            bf.u = *(const uint4*)&wp1[((ct * 8 + ks) * 64 + lane) * 8];
            acc[ct] = __builtin_amdgcn_mfma_f32_16x16x32_bf16(af.s, bf.s, acc[ct], 0, 0, 0);
        }
    }

    // relu+bias -> LDS (local rows of this wave's strip; no cross-wave sharing)
    const int lrow0 = wave * 16 + (lane >> 4) * 4;
    const int ccol = lane & 15;
#pragma unroll
    for (int ct = 0; ct < 8; ++ct) {
        const int col = ct * 16 + ccol;
        const float bv = b1[col];
#pragma unroll
        for (int r = 0; r < 4; ++r)
            sh[lrow0 + r][col] = f2b(fmaxf(acc[ct][r] + bv, 0.0f));
    }
    // wave-synchronous: each wave reads only rows it wrote; no __syncthreads needed.

    // ---- phase 2: [pq|q] strip via MFMA from LDS
    const unsigned short* aptr = &sh[wave * 16 + (lane & 15)][(lane >> 4) * 8];

    float4v acc2[5];
#pragma unroll
    for (int ct = 0; ct < 5; ++ct) acc2[ct] = (float4v){0.f, 0.f, 0.f, 0.f};

#pragma unroll
    for (int ks = 0; ks < 4; ++ks) {
        union { uint4 u; short8 s; } af;
        af.u = *(const uint4*)&aptr[ks * 32];
#pragma unroll
        for (int ct = 0; ct < 5; ++ct) {
            union { uint4 u; short8 s; } bf;
            bf.u = *(const uint4*)&wp2[((ct * 4 + ks) * 64 + lane) * 8];
            acc2[ct] = __builtin_amdgcn_mfma_f32_16x16x32_bf16(af.s, bf.s, acc2[ct], 0, 0, 0);
        }
    }

    const int crow0 = row0 + (lane >> 4) * 4;
#pragma unroll
    for (int ct = 0; ct < 5; ++ct) {
        const int col = ct * 16 + ccol;        // 0..79
#pragma unroll
        for (int r = 0; r < 4; ++r) {
            int row = crow0 + r;
            if (row < N_NODES) {
                if (col < D_OUT) {
                    pq[(unsigned)row * 40u + (unsigned)col] = f2q(acc2[ct][r]);
                } else {
                    q[(unsigned)row * 40u + (unsigned)(col - D_OUT)] = acc2[ct][r] + b2[col - D_OUT];
                }
            }
        }
    }
}

// out = log_softmax(meanagg(pq) + q): one wave per node.
// Lane = (slot s = lane/10, colgroup cg = lane%10): lane loads uint (4 fp8 cols) of
// neighbor j+s -> 6 neighbors per load instr; 4-deep unroll (24 neighbors/iter).
__global__ __launch_bounds__(256) void gather40_kernel(const unsigned char* __restrict__ pq,
                                                       const float* __restrict__ q,
                                                       const int* __restrict__ csr,
                                                       const unsigned* __restrict__ row_start,
                                                       const unsigned* __restrict__ deg,
                                                       const float* __restrict__ invc,
                                                       float* __restrict__ out) {
    __shared__ float sm[4][40];
    const int wave = threadIdx.x >> 6;
    const int lane = threadIdx.x & 63;
    const int node = blockIdx.x * 4 + wave;
    if (node >= N_NODES) return;

    const unsigned start = row_start[node];
    const unsigned cnt = deg[node];
    const int s = lane / 10;          // 0..6 (6 -> idle)
    const int cg = lane % 10;         // col group (4 cols)
    const unsigned cgo = (unsigned)(cg * 4);
    const bool gactive = s < 6;

    floatx2 a01 = (floatx2){0.f, 0.f}, a23 = (floatx2){0.f, 0.f};

    for (unsigned base = 0; base < cnt; base += 64) {
        unsigned rem = cnt - base;
        if (rem > 64u) rem = 64u;
        int nid = (lane < (int)rem) ? csr[start + base + lane] : 0;
        for (unsigned j = 0; j < rem; j += 24) {
            unsigned u[4];
#pragma unroll
            for (int t = 0; t < 4; ++t) {
                unsigned idx = j + t * 6 + s;
                int sid = __shfl(nid, (int)(idx & 63));
                bool valid = gactive && (idx < rem);
                u[t] = valid ? *(const unsigned*)&pq[(unsigned)sid * 40u + cgo] : 0u;
            }
#pragma unroll
            for (int t = 0; t < 4; ++t) {
                a01 += pkcvt<false>(u[t]);
                a23 += pkcvt<true>(u[t]);
            }
        }
    }

    float a0 = a01[0], a1 = a01[1], a2 = a23[0], a3 = a23[1];
    // reduce slots 0..5 into slot 0 (lanes 0..9), guarded to avoid pollution
    {
        float t0, t1, t2, t3;
        t0 = __shfl(a0, lane + 30); t1 = __shfl(a1, lane + 30);
        t2 = __shfl(a2, lane + 30); t3 = __shfl(a3, lane + 30);
        if (lane < 30) { a0 += t0; a1 += t1; a2 += t2; a3 += t3; }
        t0 = __shfl(a0, lane + 20); t1 = __shfl(a1, lane + 20);
        t2 = __shfl(a2, lane + 20); t3 = __shfl(a3, lane + 20);
        if (lane < 10) { a0 += t0; a1 += t1; a2 += t2; a3 += t3; }
        t0 = __shfl(a0, lane + 10); t1 = __shfl(a1, lane + 10);
        t2 = __shfl(a2, lane + 10); t3 = __shfl(a3, lane + 10);
        if (lane < 10) { a0 += t0; a1 += t1; a2 += t2; a3 += t3; }
    }
    if (lane < 10) {
        sm[wave][cg * 4 + 0] = a0;
        sm[wave][cg * 4 + 1] = a1;
        sm[wave][cg * 4 + 2] = a2;
        sm[wave][cg * 4 + 3] = a3;
    }
    // wave-synchronous LDS round-trip (no barrier needed within a wave)
    const bool active = lane < D_OUT;
    float v = active ? (sm[wave][active ? lane : 0] * invc[node]
                        + q[(unsigned)node * 40u + (unsigned)(active ? lane : 0)])
                     : -__builtin_huge_valf();
    float m = v;
#pragma unroll
    for (int off = 32; off >= 1; off >>= 1) m = fmaxf(m, __shfl_xor(m, off));
    float e = active ? expf(v - m) : 0.0f;
    float ssum = e;
#pragma unroll
    for (int off = 32; off >= 1; off >>= 1) ssum += __shfl_xor(ssum, off);
    float ls = logf(ssum);
    if (active) out[(unsigned)node * 40u + (unsigned)lane] = v - m - ls;
}

extern "C" void kernel_launch(void* const* d_in, const int* in_sizes, int n_in,
                              void* d_out, int out_size, void* d_ws, size_t ws_size,
                              hipStream_t stream) {
    const float* x   = (const float*)d_in[0];
    const void*  ei  = d_in[1];
    const float* W1l = (const float*)d_in[2];
    const float* W1r = (const float*)d_in[3];
    const float* b1  = (const float*)d_in[4];
    const float* W2l = (const float*)d_in[5];
    const float* W2r = (const float*)d_in[6];
    const float* b2  = (const float*)d_in[7];
    float* out = (float*)d_out;

    const long long E = (long long)in_sizes[1] / 2;
    const int NPB = (int)((E + CHUNK - 1) / CHUNK);

    char* ws = (char*)d_ws;
    int*      flag      = (int*)ws;
    unsigned* bcount    = (unsigned*)(ws + 4096);
    unsigned* deg       = (unsigned*)(ws + 16384);
    float*    invc      = (float*)(ws + 416384);
    unsigned* row_start = (unsigned*)(ws + 816384);
    int*      csr       = (int*)(ws + 1216384);
    unsigned short* xb  = (unsigned short*)(ws + 14016384);
    unsigned short* aggb= (unsigned short*)(ws + 39616384);
    unsigned* slab      = (unsigned*)(ws + 39616384);        // alias (dead before aggb written)
    unsigned short* wp1 = (unsigned short*)(ws + 65216384);
    unsigned short* wp2 = (unsigned short*)(ws + 65281920);
    unsigned char*  pq  = (unsigned char*)(ws + 65310720);
    float*    q         = (float*)(ws + 69310720);
    unsigned char*  xq  = (unsigned char*)(ws + 90910720);

    // cast + pack_w + detect + bcount-zero in one horizontal launch
    prep_kernel<<<CAST_BLOCKS + 21 + 1, 256, 0, stream>>>(x, xb, xq, W1l, W1r, W2l, W2r,
                                                          wp1, wp2, (const int*)ei, flag, bcount);

    // CSR build: LDS counting-sort partition (8192 edges/block) -> per-bucket build
    partition_kernel<<<NPB, 1024, 0, stream>>>(ei, flag, bcount, slab, E);
    build_kernel<<<NBUCK, 256, 0, stream>>>(slab, bcount, deg, invc, row_start, csr);

    // layer 1: fp8 gather-mean of x, then fused GEMM1+GEMM2 (h stays in LDS)
    gather_fp8_kernel<<<(N_NODES + 3) / 4, 256, 0, stream>>>(xq, csr, row_start, deg, invc, aggb);
    gemm12_kernel<<<(N_NODES + 63) / 64, 256, 0, stream>>>(aggb, xb, wp1, b1, wp2, b2, pq, q);

    // layer 2 gather-mean + log_softmax
    gather40_kernel<<<(N_NODES + 3) / 4, 256, 0, stream>>>(pq, q, csr, row_start, deg, invc, out);
}

// Round 10
// 301.693 us; speedup vs baseline: 1.0887x; 1.0219x over previous
//
#include <hip/hip_runtime.h>
#include <hip/hip_bf16.h>
#include <hip/hip_fp8.h>
#include <math.h>

#define N_NODES 100000
#define D_IN    128
#define D_HID   128
#define D_OUT   40
#define NBUCK   391      // ceil(100000/256), bucket = dst >> 8
#define CHUNK   8192     // edges per partition block (1024 threads, 8 edges/thread)
#define SLABCAP 16320    // per-bucket slab capacity (mean 8184, sigma~90 -> no overflow)
#define CAST_BLOCKS_1K 1563  // ceil(100000*128/8 / 1024)

// ---------------- workspace layout (bytes) ----------------
// flag      : 0          (4)
// bcount    : 4096       (1564)
// deg       : 16384      (400,000 u32)
// invc      : 416,384    (400,000 f32)
// row_start : 816,384    (400,000 u32)
// csr       : 1,216,384  (12,800,000 i32)             ends 14,016,384
// xb (bf16) : 14,016,384 (25,600,000)                 ends 39,616,384
// aggb(bf16): 39,616,384 (25,600,000)                 ends 65,216,384
//   alias before aggb written: slab (u32, NBUCK*16320*4 = 25,524,480) @39,616,384
// wp1 (bf16): 65,216,384 (65,536)                     ends 65,281,920
// wp2 (bf16): 65,281,920 (20,480)                     ends 65,302,400 (pad to 65,310,720)
// pq  (fp8) : 65,310,720 (4,000,000)                  ends 69,310,720
// q   (f32) : 69,310,720 (16,000,000)                 ends 85,310,720
// xq  (fp8) : 90,910,720 (12,800,000)                 ends 103,710,720

using short8  = __attribute__((ext_vector_type(8))) short;
using float4v = __attribute__((ext_vector_type(4))) float;
using floatx2 = __attribute__((ext_vector_type(2))) float;

__device__ __forceinline__ unsigned short f2b(float f) {
    __hip_bfloat16 b = __float2bfloat16(f);
    return *(unsigned short*)&b;
}
__device__ __forceinline__ unsigned packb(float a, float b) {
    return (unsigned)f2b(a) | ((unsigned)f2b(b) << 16);
}

__device__ __forceinline__ unsigned char f2q(float f) {
    __hip_fp8_e4m3 v(f);
    return *(unsigned char*)&v;
}
template <int SEL>
__device__ __forceinline__ float q2f(unsigned u) {
#if __has_builtin(__builtin_amdgcn_cvt_f32_fp8)
    return __builtin_amdgcn_cvt_f32_fp8((int)u, SEL);
#else
    unsigned char b = (u >> (SEL * 8)) & 0xff;
    __hip_fp8_e4m3 v;
    *(unsigned char*)&v = b;
    return (float)v;
#endif
}
// packed: convert 2 fp8 to float2 in one instr
template <bool HI>
__device__ __forceinline__ floatx2 pkcvt(unsigned u) {
#if __has_builtin(__builtin_amdgcn_cvt_pk_f32_fp8)
    return __builtin_amdgcn_cvt_pk_f32_fp8((int)u, HI);
#else
    floatx2 r;
    if constexpr (HI) { r[0] = q2f<2>(u); r[1] = q2f<3>(u); }
    else              { r[0] = q2f<0>(u); r[1] = q2f<1>(u); }
    return r;
#endif
}

__device__ __forceinline__ long long edge_at(const void* ei, int is64, long long idx) {
    if (is64) return ((const long long*)ei)[idx];
    return (long long)((const int*)ei)[idx];
}

// Tiny init: detect int64 vs int32 edge_index + zero bcount (one block).
__global__ __launch_bounds__(256) void init_kernel(const int* __restrict__ ei,
                                                   int* __restrict__ flag,
                                                   unsigned* __restrict__ bcount) {
    const int t = threadIdx.x;
    if (t < 64) {
        int ok = 1;
#pragma unroll
        for (int k = 0; k < 4; ++k) {
            if (ei[2 * (t * 4 + k) + 1] != 0) ok = 0;
        }
        int all0 = __all(ok);
        if (t == 0) *flag = all0 ? 1 : 0;
    }
    if (t < NBUCK) bcount[t] = 0u;
    if (t + 256 < NBUCK) bcount[t + 256] = 0u;
}

// Mega-kernel: horizontal fusion of the two independent front-end chains.
//   blocks [0, npb)                 : partition (LDS counting sort of edges)
//   blocks [npb, npb+1563)          : cast x -> xb (bf16) + xq (fp8)
//   blocks [npb+1563, npb+1563+6)   : pack W1/W2 into MFMA B-fragment order
// Partition blocks get low blockIdx -> scheduled first -> build's input ready
// earliest; cast streaming overlaps partition's LDS/atomic phases.
__global__ __launch_bounds__(1024) void mega_kernel(const void* __restrict__ ei,
                                                    const int* __restrict__ flag,
                                                    unsigned* __restrict__ bcount,
                                                    unsigned* __restrict__ slab,
                                                    long long E, int npb,
                                                    const float* __restrict__ x,
                                                    unsigned short* __restrict__ xb,
                                                    unsigned char* __restrict__ xq,
                                                    const float* __restrict__ W1l,
                                                    const float* __restrict__ W1r,
                                                    const float* __restrict__ W2l,
                                                    const float* __restrict__ W2r,
                                                    unsigned short* __restrict__ wp1,
                                                    unsigned short* __restrict__ wp2) {
    __shared__ unsigned hist[NBUCK];     // counts, then cursor
    __shared__ unsigned lstart[NBUCK];   // local exclusive offsets
    __shared__ unsigned gofs[NBUCK];     // b*SLABCAP + gbase - lstart[b]
    __shared__ unsigned s[512];
    __shared__ unsigned wsum[16];
    __shared__ unsigned rec[CHUNK];
    __shared__ unsigned short bkt[CHUNK];

    const int blk = blockIdx.x;
    const int tid = threadIdx.x;

    if (blk >= npb) {
        const int cb = blk - npb;
        if (cb < CAST_BLOCKS_1K) {
            // ---- cast: x (f32 [N,128]) -> xb (bf16) + xq (fp8 e4m3)
            long long i = ((long long)cb * 1024 + tid) * 8;
            if (i >= (long long)N_NODES * 128) return;
            float4 a = *(const float4*)&x[i];
            float4 c = *(const float4*)&x[i + 4];
            ushort4 o0, o1;
            o0.x = f2b(a.x); o0.y = f2b(a.y); o0.z = f2b(a.z); o0.w = f2b(a.w);
            o1.x = f2b(c.x); o1.y = f2b(c.y); o1.z = f2b(c.z); o1.w = f2b(c.w);
            *(ushort4*)&xb[i] = o0;
            *(ushort4*)&xb[i + 4] = o1;
            uint2 p;
            p.x = (unsigned)f2q(a.x) | ((unsigned)f2q(a.y) << 8)
                | ((unsigned)f2q(a.z) << 16) | ((unsigned)f2q(a.w) << 24);
            p.y = (unsigned)f2q(c.x) | ((unsigned)f2q(c.y) << 8)
                | ((unsigned)f2q(c.z) << 16) | ((unsigned)f2q(c.w) << 24);
            *(uint2*)&xq[i] = p;
        } else {
            // ---- pack weights into MFMA B-fragment order (bf16)
            int t = (cb - CAST_BLOCKS_1K) * 1024 + tid;
            if (t < 4096) {                     // wp1 entries (ct,ks,lane)
                int lane = t & 63;
                int ks = (t >> 6) & 7;
                int ct = t >> 9;
                int n = ct * 16 + (lane & 15);
                int kr = (lane >> 4) * 8;
                unsigned short v[8];
#pragma unroll
                for (int j = 0; j < 8; ++j) {
                    int k = ks * 32 + kr + j;
                    float f = (k < 128) ? W1l[k * 128 + n] : W1r[(k - 128) * 128 + n];
                    v[j] = f2b(f);
                }
                ushort4 o0 = {v[0], v[1], v[2], v[3]};
                ushort4 o1 = {v[4], v[5], v[6], v[7]};
                *(ushort4*)&wp1[t * 8] = o0;
                *(ushort4*)&wp1[t * 8 + 4] = o1;
            } else if (t < 4096 + 1280) {       // wp2 entries
                int u = t - 4096;
                int lane = u & 63;
                int ks = (u >> 6) & 3;
                int ct = u >> 8;
                int n = ct * 16 + (lane & 15);
                int kr = (lane >> 4) * 8;
                unsigned short v[8];
#pragma unroll
                for (int j = 0; j < 8; ++j) {
                    int k = ks * 32 + kr + j;
                    float f = (n < 40) ? W2l[k * 40 + n] : W2r[k * 40 + (n - 40)];
                    v[j] = f2b(f);
                }
                ushort4 o0 = {v[0], v[1], v[2], v[3]};
                ushort4 o1 = {v[4], v[5], v[6], v[7]};
                *(ushort4*)&wp2[u * 8] = o0;
                *(ushort4*)&wp2[u * 8 + 4] = o1;
            }
        }
        return;
    }

    // ---- partition: block-level LDS counting sort, coalesced slab writes
    const int lane = tid & 63;
    const int w = tid >> 6;              // wave 0..15
    const int is64 = *flag;
    const long long cb64 = (long long)blk * CHUNK;
    const unsigned n = (unsigned)(((E - cb64) < (long long)CHUNK) ? (E - cb64) : CHUNK);

    if (tid < NBUCK) hist[tid] = 0;
    __syncthreads();

    // pass 1: load edges ONCE into registers + histogram
    unsigned esrc[CHUNK / 1024], edst[CHUNK / 1024];
#pragma unroll
    for (int j = 0; j < CHUNK / 1024; ++j) {
        unsigned e = j * 1024 + tid;
        if (e < n) {
            esrc[j] = (unsigned)edge_at(ei, is64, cb64 + e);
            edst[j] = (unsigned)edge_at(ei, is64, E + cb64 + e);
            atomicAdd(&hist[edst[j] >> 8], 1u);
        }
    }
    __syncthreads();

    // inclusive scan of hist via wave shfl-scan + cross-wave fixup
    {
        unsigned v0 = (tid < NBUCK) ? hist[tid] : 0u;
        unsigned xx = v0;
#pragma unroll
        for (int off = 1; off < 64; off <<= 1) {
            unsigned t = __shfl_up(xx, off);
            if (lane >= off) xx += t;
        }
        if (lane == 63) wsum[w] = xx;
        __syncthreads();
        if (w == 0) {
            unsigned y = (lane < 16) ? wsum[lane] : 0u;
#pragma unroll
            for (int off = 1; off < 16; off <<= 1) {
                unsigned t = __shfl_up(y, off);
                if (lane >= off) y += t;
            }
            if (lane < 16) wsum[lane] = y;
        }
        __syncthreads();
        unsigned pre = (w > 0) ? wsum[w - 1] : 0u;
        if (tid < NBUCK) s[tid] = xx + pre;   // inclusive scan
    }
    if (tid < NBUCK) {
        unsigned cnt = hist[tid];
        unsigned ex = s[tid] - cnt;
        lstart[tid] = ex;
        if (cnt) {
            unsigned g = atomicAdd(&bcount[tid], cnt);
            gofs[tid] = (unsigned)(tid * SLABCAP) + g - ex;
        }
        hist[tid] = 0;   // reuse as cursor
    }
    __syncthreads();

    // pass 2: scatter into LDS from registers, bucket-grouped
#pragma unroll
    for (int j = 0; j < CHUNK / 1024; ++j) {
        unsigned e = j * 1024 + tid;
        if (e < n) {
            unsigned d = edst[j];
            unsigned b = d >> 8;
            unsigned loc = atomicAdd(&hist[b], 1u);
            unsigned slot = lstart[b] + loc;
            rec[slot] = ((d & 255u) << 17) | esrc[j];
            bkt[slot] = (unsigned short)b;
        }
    }
    __syncthreads();

    // pass 3: coalesced global writes
#pragma unroll
    for (int j = 0; j < CHUNK / 1024; ++j) {
        unsigned i = j * 1024 + tid;
        if (i < n) {
            unsigned b = bkt[i];
            slab[gofs[b] + i] = rec[i];
        }
    }
}

// Per-bucket fine CSR build in LDS (reads slab, writes csr at prefix offsets).
// Inline exclusive prefix of bcount; wave-level reductions/scans.
__global__ __launch_bounds__(256) void build_kernel(const unsigned* __restrict__ slab,
                                                    const unsigned* __restrict__ bcount,
                                                    unsigned* __restrict__ deg,
                                                    float* __restrict__ invc,
                                                    unsigned* __restrict__ row_start,
                                                    int* __restrict__ csr) {
    __shared__ unsigned red[4];
    __shared__ unsigned ws[4];
    __shared__ unsigned cnt[256];
    const int tid = threadIdx.x;
    const int lane = tid & 63;
    const int w = tid >> 6;              // wave 0..3
    const int nb = blockIdx.x << 8;
    const long long sb = (long long)blockIdx.x * SLABCAP;

    // exclusive prefix: es = sum of bcount[0..blockIdx.x)
    unsigned pv = 0;
    for (unsigned i = tid; i < (unsigned)blockIdx.x; i += 256) pv += bcount[i];
#pragma unroll
    for (int off = 32; off >= 1; off >>= 1) pv += __shfl_xor(pv, off);
    if (lane == 0) red[w] = pv;
    __syncthreads();
    const unsigned es = red[0] + red[1] + red[2] + red[3];
    const unsigned n  = bcount[blockIdx.x];

    cnt[tid] = 0;
    __syncthreads();
    for (unsigned i = tid; i < n; i += 256) {
        unsigned d = slab[sb + i] >> 17;
        atomicAdd(&cnt[d], 1u);
    }
    __syncthreads();
    unsigned v = cnt[tid];
    // inclusive wave scan + cross-wave fixup
    unsigned x = v;
#pragma unroll
    for (int off = 1; off < 64; off <<= 1) {
        unsigned t = __shfl_up(x, off);
        if (lane >= off) x += t;
    }
    if (lane == 63) ws[w] = x;
    __syncthreads();
    unsigned pre = 0;
#pragma unroll
    for (int k = 0; k < 4; ++k) if (k < w) pre += ws[k];
    unsigned ex = x + pre - v;
    int node = nb + tid;
    if (node < N_NODES) {
        deg[node] = v;
        invc[node] = 1.0f / fmaxf((float)v, 1.0f);
        row_start[node] = es + ex;
    }
    __syncthreads();
    cnt[tid] = ex;   // reuse as cursor
    __syncthreads();
    for (unsigned i = tid; i < n; i += 256) {
        unsigned pr = slab[sb + i];
        unsigned d = pr >> 17;
        unsigned pos = es + atomicAdd(&cnt[d], 1u);
        csr[pos] = (int)(pr & 0x1FFFFu);
    }
}

// Gather-mean over 128 fp8 cols -> bf16 agg: one wave per node.
// Lane = (slot s = lane>>4, colgroup cg = lane&15): lane loads uint2 (8 fp8 cols) of
// neighbor j+s -> 4 neighbors per wave-load; packed cvt+add (2 elems/instr).
__global__ __launch_bounds__(256) void gather_fp8_kernel(const unsigned char* __restrict__ featq,
                                                         const int* __restrict__ csr,
                                                         const unsigned* __restrict__ row_start,
                                                         const unsigned* __restrict__ deg,
                                                         const float* __restrict__ invc,
                                                         unsigned short* __restrict__ aggb) {
    const int wave = threadIdx.x >> 6;
    const int lane = threadIdx.x & 63;
    const int node = blockIdx.x * 4 + wave;
    if (node >= N_NODES) return;

    const unsigned start = row_start[node];
    const unsigned cnt = deg[node];
    const int s = lane >> 4;              // slot 0..3
    const unsigned cgo = (unsigned)((lane & 15) * 8);   // col-group byte offset

    floatx2 acc[4];
#pragma unroll
    for (int k = 0; k < 4; ++k) acc[k] = (floatx2){0.f, 0.f};

    for (unsigned base = 0; base < cnt; base += 64) {
        unsigned rem = cnt - base;
        if (rem > 64u) rem = 64u;
        int nid = (lane < (int)rem) ? csr[start + base + lane] : 0;
        for (unsigned j = 0; j < rem; j += 8) {
            uint2 u0 = {0u, 0u}, u1 = {0u, 0u};
            unsigned i0 = j + s;
            unsigned i1 = j + 4 + s;
            int s0 = __shfl(nid, (int)(i0 & 63));
            int s1 = __shfl(nid, (int)(i1 & 63));
            if (i0 < rem) u0 = *(const uint2*)&featq[((unsigned)s0 << 7) + cgo];
            if (i1 < rem) u1 = *(const uint2*)&featq[((unsigned)s1 << 7) + cgo];
            acc[0] += pkcvt<false>(u0.x); acc[1] += pkcvt<true>(u0.x);
            acc[2] += pkcvt<false>(u0.y); acc[3] += pkcvt<true>(u0.y);
            acc[0] += pkcvt<false>(u1.x); acc[1] += pkcvt<true>(u1.x);
            acc[2] += pkcvt<false>(u1.y); acc[3] += pkcvt<true>(u1.y);
        }
    }

    // reduce across the 4 slots (lanes differing in bits 4,5)
#pragma unroll
    for (int k = 0; k < 4; ++k) {
        acc[k][0] += __shfl_xor(acc[k][0], 16);
        acc[k][1] += __shfl_xor(acc[k][1], 16);
        acc[k][0] += __shfl_xor(acc[k][0], 32);
        acc[k][1] += __shfl_xor(acc[k][1], 32);
    }

    if (lane < 16) {
        const float ic = invc[node];
        uint4 o;
        o.x = packb(acc[0][0] * ic, acc[0][1] * ic);
        o.y = packb(acc[1][0] * ic, acc[1][1] * ic);
        o.z = packb(acc[2][0] * ic, acc[2][1] * ic);
        o.w = packb(acc[3][0] * ic, acc[3][1] * ic);
        *(uint4*)&aggb[(unsigned)node * 128u + cgo] = o;
    }
}

// Fused layer-1 GEMM + layer-2 projection: h = relu([aggb|xb]@wp1 + b1) stays in LDS,
// then [pq|q] = h@wp2 (+b2 on q half). 64 rows/block, 4 waves.
__global__ __launch_bounds__(256) void gemm12_kernel(const unsigned short* __restrict__ aggb,
                                                     const unsigned short* __restrict__ xb,
                                                     const unsigned short* __restrict__ wp1,
                                                     const float* __restrict__ b1,
                                                     const unsigned short* __restrict__ wp2,
                                                     const float* __restrict__ b2,
                                                     unsigned char* __restrict__ pq,
                                                     float* __restrict__ q) {
    __shared__ unsigned short sh[64][136];   // h rows (bf16), stride 272B (16B-aligned)
    const int wave = threadIdx.x >> 6;
    const int lane = threadIdx.x & 63;
    const int row0 = blockIdx.x * 64 + wave * 16;
    const unsigned abase = (unsigned)(row0 + (lane & 15)) * 128u + (unsigned)((lane >> 4) * 8);

    // ---- phase 1: h-strip via MFMA
    float4v acc[8];
#pragma unroll
    for (int ct = 0; ct < 8; ++ct) acc[ct] = (float4v){0.f, 0.f, 0.f, 0.f};

#pragma unroll
    for (int ks = 0; ks < 8; ++ks) {
        union { uint4 u; short8 s; } af;
        if (ks < 4) af.u = *(const uint4*)&aggb[abase + ks * 32];
        else        af.u = *(const uint4*)&xb[abase + (ks - 4) * 32];
#pragma unroll
        for (int ct = 0; ct < 8; ++ct) {
            union { uint4 u; short8 s; } bf;
            bf.u = *(const uint4*)&wp1[((ct * 8 + ks) * 64 + lane) * 8];
            acc[ct] = __builtin_amdgcn_mfma_f32_16x16x32_bf16(af.s, bf.s, acc[ct], 0, 0, 0);
        }
    }

    // relu+bias -> LDS (local rows of this wave's strip; no cross-wave sharing)
    const int lrow0 = wave * 16 + (lane >> 4) * 4;
    const int ccol = lane & 15;
#pragma unroll
    for (int ct = 0; ct < 8; ++ct) {
        const int col = ct * 16 + ccol;
        const float bv = b1[col];
#pragma unroll
        for (int r = 0; r < 4; ++r)
            sh[lrow0 + r][col] = f2b(fmaxf(acc[ct][r] + bv, 0.0f));
    }
    // wave-synchronous: each wave reads only rows it wrote; no __syncthreads needed.

    // ---- phase 2: [pq|q] strip via MFMA from LDS
    const unsigned short* aptr = &sh[wave * 16 + (lane & 15)][(lane >> 4) * 8];

    float4v acc2[5];
#pragma unroll
    for (int ct = 0; ct < 5; ++ct) acc2[ct] = (float4v){0.f, 0.f, 0.f, 0.f};

#pragma unroll
    for (int ks = 0; ks < 4; ++ks) {
        union { uint4 u; short8 s; } af;
        af.u = *(const uint4*)&aptr[ks * 32];
#pragma unroll
        for (int ct = 0; ct < 5; ++ct) {
            union { uint4 u; short8 s; } bf;
            bf.u = *(const uint4*)&wp2[((ct * 4 + ks) * 64 + lane) * 8];
            acc2[ct] = __builtin_amdgcn_mfma_f32_16x16x32_bf16(af.s, bf.s, acc2[ct], 0, 0, 0);
        }
    }

    const int crow0 = row0 + (lane >> 4) * 4;
#pragma unroll
    for (int ct = 0; ct < 5; ++ct) {
        const int col = ct * 16 + ccol;        // 0..79
#pragma unroll
        for (int r = 0; r < 4; ++r) {
            int row = crow0 + r;
            if (row < N_NODES) {
                if (col < D_OUT) {
                    pq[(unsigned)row * 40u + (unsigned)col] = f2q(acc2[ct][r]);
                } else {
                    q[(unsigned)row * 40u + (unsigned)(col - D_OUT)] = acc2[ct][r] + b2[col - D_OUT];
                }
            }
        }
    }
}

// out = log_softmax(meanagg(pq) + q): one wave per node.
// Lane = (slot s = lane/10, colgroup cg = lane%10): lane loads uint (4 fp8 cols) of
// neighbor j+s -> 6 neighbors per load instr; 4-deep unroll (24 neighbors/iter).
__global__ __launch_bounds__(256) void gather40_kernel(const unsigned char* __restrict__ pq,
                                                       const float* __restrict__ q,
                                                       const int* __restrict__ csr,
                                                       const unsigned* __restrict__ row_start,
                                                       const unsigned* __restrict__ deg,
                                                       const float* __restrict__ invc,
                                                       float* __restrict__ out) {
    __shared__ float sm[4][40];
    const int wave = threadIdx.x >> 6;
    const int lane = threadIdx.x & 63;
    const int node = blockIdx.x * 4 + wave;
    if (node >= N_NODES) return;

    const unsigned start = row_start[node];
    const unsigned cnt = deg[node];
    const int s = lane / 10;          // 0..6 (6 -> idle)
    const int cg = lane % 10;         // col group (4 cols)
    const unsigned cgo = (unsigned)(cg * 4);
    const bool gactive = s < 6;

    floatx2 a01 = (floatx2){0.f, 0.f}, a23 = (floatx2){0.f, 0.f};

    for (unsigned base = 0; base < cnt; base += 64) {
        unsigned rem = cnt - base;
        if (rem > 64u) rem = 64u;
        int nid = (lane < (int)rem) ? csr[start + base + lane] : 0;
        for (unsigned j = 0; j < rem; j += 24) {
            unsigned u[4];
#pragma unroll
            for (int t = 0; t < 4; ++t) {
                unsigned idx = j + t * 6 + s;
                int sid = __shfl(nid, (int)(idx & 63));
                bool valid = gactive && (idx < rem);
                u[t] = valid ? *(const unsigned*)&pq[(unsigned)sid * 40u + cgo] : 0u;
            }
#pragma unroll
            for (int t = 0; t < 4; ++t) {
                a01 += pkcvt<false>(u[t]);
                a23 += pkcvt<true>(u[t]);
            }
        }
    }

    float a0 = a01[0], a1 = a01[1], a2 = a23[0], a3 = a23[1];
    // reduce slots 0..5 into slot 0 (lanes 0..9), guarded to avoid pollution
    {
        float t0, t1, t2, t3;
        t0 = __shfl(a0, lane + 30); t1 = __shfl(a1, lane + 30);
        t2 = __shfl(a2, lane + 30); t3 = __shfl(a3, lane + 30);
        if (lane < 30) { a0 += t0; a1 += t1; a2 += t2; a3 += t3; }
        t0 = __shfl(a0, lane + 20); t1 = __shfl(a1, lane + 20);
        t2 = __shfl(a2, lane + 20); t3 = __shfl(a3, lane + 20);
        if (lane < 10) { a0 += t0; a1 += t1; a2 += t2; a3 += t3; }
        t0 = __shfl(a0, lane + 10); t1 = __shfl(a1, lane + 10);
        t2 = __shfl(a2, lane + 10); t3 = __shfl(a3, lane + 10);
        if (lane < 10) { a0 += t0; a1 += t1; a2 += t2; a3 += t3; }
    }
    if (lane < 10) {
        sm[wave][cg * 4 + 0] = a0;
        sm[wave][cg * 4 + 1] = a1;
        sm[wave][cg * 4 + 2] = a2;
        sm[wave][cg * 4 + 3] = a3;
    }
    // wave-synchronous LDS round-trip (no barrier needed within a wave)
    const bool active = lane < D_OUT;
    float v = active ? (sm[wave][active ? lane : 0] * invc[node]
                        + q[(unsigned)node * 40u + (unsigned)(active ? lane : 0)])
                     : -__builtin_huge_valf();
    float m = v;
#pragma unroll
    for (int off = 32; off >= 1; off >>= 1) m = fmaxf(m, __shfl_xor(m, off));
    float e = active ? expf(v - m) : 0.0f;
    float ssum = e;
#pragma unroll
    for (int off = 32; off >= 1; off >>= 1) ssum += __shfl_xor(ssum, off);
    float ls = logf(ssum);
    if (active) out[(unsigned)node * 40u + (unsigned)lane] = v - m - ls;
}

extern "C" void kernel_launch(void* const* d_in, const int* in_sizes, int n_in,
                              void* d_out, int out_size, void* d_ws, size_t ws_size,
                              hipStream_t stream) {
    const float* x   = (const float*)d_in[0];
    const void*  ei  = d_in[1];
    const float* W1l = (const float*)d_in[2];
    const float* W1r = (const float*)d_in[3];
    const float* b1  = (const float*)d_in[4];
    const float* W2l = (const float*)d_in[5];
    const float* W2r = (const float*)d_in[6];
    const float* b2  = (const float*)d_in[7];
    float* out = (float*)d_out;

    const long long E = (long long)in_sizes[1] / 2;
    const int NPB = (int)((E + CHUNK - 1) / CHUNK);

    char* ws = (char*)d_ws;
    int*      flag      = (int*)ws;
    unsigned* bcount    = (unsigned*)(ws + 4096);
    unsigned* deg       = (unsigned*)(ws + 16384);
    float*    invc      = (float*)(ws + 416384);
    unsigned* row_start = (unsigned*)(ws + 816384);
    int*      csr       = (int*)(ws + 1216384);
    unsigned short* xb  = (unsigned short*)(ws + 14016384);
    unsigned short* aggb= (unsigned short*)(ws + 39616384);
    unsigned* slab      = (unsigned*)(ws + 39616384);        // alias (dead before aggb written)
    unsigned short* wp1 = (unsigned short*)(ws + 65216384);
    unsigned short* wp2 = (unsigned short*)(ws + 65281920);
    unsigned char*  pq  = (unsigned char*)(ws + 65310720);
    float*    q         = (float*)(ws + 69310720);
    unsigned char*  xq  = (unsigned char*)(ws + 90910720);

    // tiny init: detect + zero bcount
    init_kernel<<<1, 256, 0, stream>>>((const int*)ei, flag, bcount);

    // mega: partition-blocks first (build depends on them), then cast + pack_w
    mega_kernel<<<NPB + CAST_BLOCKS_1K + 6, 1024, 0, stream>>>(
        ei, flag, bcount, slab, E, NPB,
        x, xb, xq, W1l, W1r, W2l, W2r, wp1, wp2);

    build_kernel<<<NBUCK, 256, 0, stream>>>(slab, bcount, deg, invc, row_start, csr);

    // layer 1: fp8 gather-mean of x, then fused GEMM1+GEMM2 (h stays in LDS)
    gather_fp8_kernel<<<(N_NODES + 3) / 4, 256, 0, stream>>>(xq, csr, row_start, deg, invc, aggb);
    gemm12_kernel<<<(N_NODES + 63) / 64, 256, 0, stream>>>(aggb, xb, wp1, b1, wp2, b2, pq, q);

    // layer 2 gather-mean + log_softmax
    gather40_kernel<<<(N_NODES + 3) / 4, 256, 0, stream>>>(pq, q, csr, row_start, deg, invc, out);
}

// Round 11
// 296.269 us; speedup vs baseline: 1.1087x; 1.0183x over previous
//
#include <hip/hip_runtime.h>
#include <hip/hip_bf16.h>
#include <hip/hip_fp8.h>
#include <math.h>

#define N_NODES 100000
#define D_IN    128
#define D_HID   128
#define D_OUT   40
#define NBUCK   391      // ceil(100000/256), bucket = dst >> 8
#define CHUNK   8192     // edges per partition block (1024 threads, 8 edges/thread)
#define STAGECAP 12160   // per-bucket staging capacity (mean 8184, sigma~90)
#define CAST_BLOCKS_1K 1563  // ceil(100000*128/8 / 1024)

// ---------------- workspace layout (bytes) ----------------
// deg       : 16384      (400,000 u32)
// invc      : 416,384    (400,000 f32)
// row_start : 816,384    (400,000 u32)
// csr       : 1,216,384  (12,800,000 i32)             ends 14,016,384
// xb (bf16) : 14,016,384 (25,600,000)                 ends 39,616,384
// aggb(bf16): 39,616,384 (25,600,000)                 ends 65,216,384
//   alias before aggb written: slab (u32, NPB*CHUNK*4 = 12,812,288) @39,616,384
// wp1 (bf16): 65,216,384 (65,536)                     ends 65,281,920
// wp2 (bf16): 65,281,920 (20,480)                     ends 65,302,400 (pad to 65,310,720)
// pq  (fp8) : 65,310,720 (4,000,000)                  ends 69,310,720
// q   (f32) : 69,310,720 (16,000,000)                 ends 85,310,720
// xq  (fp8) : 90,910,720 (12,800,000)                 ends 103,710,720
// lofs(u32) : 103,710,720 (392 * NPB * 4 = 613,088)   ends 104,323,808

using short8  = __attribute__((ext_vector_type(8))) short;
using float4v = __attribute__((ext_vector_type(4))) float;
using floatx2 = __attribute__((ext_vector_type(2))) float;

__device__ __forceinline__ unsigned short f2b(float f) {
    __hip_bfloat16 b = __float2bfloat16(f);
    return *(unsigned short*)&b;
}
__device__ __forceinline__ unsigned packb(float a, float b) {
    return (unsigned)f2b(a) | ((unsigned)f2b(b) << 16);
}

__device__ __forceinline__ unsigned char f2q(float f) {
    __hip_fp8_e4m3 v(f);
    return *(unsigned char*)&v;
}
template <int SEL>
__device__ __forceinline__ float q2f(unsigned u) {
#if __has_builtin(__builtin_amdgcn_cvt_f32_fp8)
    return __builtin_amdgcn_cvt_f32_fp8((int)u, SEL);
#else
    unsigned char b = (u >> (SEL * 8)) & 0xff;
    __hip_fp8_e4m3 v;
    *(unsigned char*)&v = b;
    return (float)v;
#endif
}
// packed: convert 2 fp8 to float2 in one instr
template <bool HI>
__device__ __forceinline__ floatx2 pkcvt(unsigned u) {
#if __has_builtin(__builtin_amdgcn_cvt_pk_f32_fp8)
    return __builtin_amdgcn_cvt_pk_f32_fp8((int)u, HI);
#else
    floatx2 r;
    if constexpr (HI) { r[0] = q2f<2>(u); r[1] = q2f<3>(u); }
    else              { r[0] = q2f<0>(u); r[1] = q2f<1>(u); }
    return r;
#endif
}

__device__ __forceinline__ long long edge_at(const void* ei, int is64, long long idx) {
    if (is64) return ((const long long*)ei)[idx];
    return (long long)((const int*)ei)[idx];
}

// Mega-kernel: horizontal fusion of the two independent front-end chains.
//   blocks [0, npb)                 : partition (LDS counting sort -> block-major slab + lofs)
//   blocks [npb, npb+1563)          : cast x -> xb (bf16) + xq (fp8)
//   blocks [npb+1563, ...)          : pack W1/W2 into MFMA B-fragment order
// No global atomics, no init dependency: each partition block derives the int64
// flag locally and writes deterministic block-local slab offsets.
__global__ __launch_bounds__(1024) void mega_kernel(const void* __restrict__ ei,
                                                    unsigned* __restrict__ slab,
                                                    unsigned* __restrict__ lofs,
                                                    long long E, int npb,
                                                    const float* __restrict__ x,
                                                    unsigned short* __restrict__ xb,
                                                    unsigned char* __restrict__ xq,
                                                    const float* __restrict__ W1l,
                                                    const float* __restrict__ W1r,
                                                    const float* __restrict__ W2l,
                                                    const float* __restrict__ W2r,
                                                    unsigned short* __restrict__ wp1,
                                                    unsigned short* __restrict__ wp2) {
    __shared__ unsigned hist[NBUCK];     // counts, then cursor
    __shared__ unsigned lstart[NBUCK];   // local exclusive offsets
    __shared__ unsigned wsum[16];
    __shared__ unsigned rec[CHUNK];
    __shared__ int sflag[1];

    const int blk = blockIdx.x;
    const int tid = threadIdx.x;

    if (blk >= npb) {
        const int cb = blk - npb;
        if (cb < CAST_BLOCKS_1K) {
            // ---- cast: x (f32 [N,128]) -> xb (bf16) + xq (fp8 e4m3)
            long long i = ((long long)cb * 1024 + tid) * 8;
            if (i >= (long long)N_NODES * 128) return;
            float4 a = *(const float4*)&x[i];
            float4 c = *(const float4*)&x[i + 4];
            ushort4 o0, o1;
            o0.x = f2b(a.x); o0.y = f2b(a.y); o0.z = f2b(a.z); o0.w = f2b(a.w);
            o1.x = f2b(c.x); o1.y = f2b(c.y); o1.z = f2b(c.z); o1.w = f2b(c.w);
            *(ushort4*)&xb[i] = o0;
            *(ushort4*)&xb[i + 4] = o1;
            uint2 p;
            p.x = (unsigned)f2q(a.x) | ((unsigned)f2q(a.y) << 8)
                | ((unsigned)f2q(a.z) << 16) | ((unsigned)f2q(a.w) << 24);
            p.y = (unsigned)f2q(c.x) | ((unsigned)f2q(c.y) << 8)
                | ((unsigned)f2q(c.z) << 16) | ((unsigned)f2q(c.w) << 24);
            *(uint2*)&xq[i] = p;
        } else {
            // ---- pack weights into MFMA B-fragment order (bf16)
            int t = (cb - CAST_BLOCKS_1K) * 1024 + tid;
            if (t < 4096) {                     // wp1 entries (ct,ks,lane)
                int lane = t & 63;
                int ks = (t >> 6) & 7;
                int ct = t >> 9;
                int n = ct * 16 + (lane & 15);
                int kr = (lane >> 4) * 8;
                unsigned short v[8];
#pragma unroll
                for (int j = 0; j < 8; ++j) {
                    int k = ks * 32 + kr + j;
                    float f = (k < 128) ? W1l[k * 128 + n] : W1r[(k - 128) * 128 + n];
                    v[j] = f2b(f);
                }
                ushort4 o0 = {v[0], v[1], v[2], v[3]};
                ushort4 o1 = {v[4], v[5], v[6], v[7]};
                *(ushort4*)&wp1[t * 8] = o0;
                *(ushort4*)&wp1[t * 8 + 4] = o1;
            } else if (t < 4096 + 1280) {       // wp2 entries
                int u = t - 4096;
                int lane = u & 63;
                int ks = (u >> 6) & 3;
                int ct = u >> 8;
                int n = ct * 16 + (lane & 15);
                int kr = (lane >> 4) * 8;
                unsigned short v[8];
#pragma unroll
                for (int j = 0; j < 8; ++j) {
                    int k = ks * 32 + kr + j;
                    float f = (n < 40) ? W2l[k * 40 + n] : W2r[k * 40 + (n - 40)];
                    v[j] = f2b(f);
                }
                ushort4 o0 = {v[0], v[1], v[2], v[3]};
                ushort4 o1 = {v[4], v[5], v[6], v[7]};
                *(ushort4*)&wp2[u * 8] = o0;
                *(ushort4*)&wp2[u * 8 + 4] = o1;
            }
        }
        return;
    }

    // ---- partition: block-level LDS counting sort -> block-major slab + lofs
    const int lane = tid & 63;
    const int w = tid >> 6;              // wave 0..15

    // local int64-vs-int32 detect (wave 0; first 256 logical values, L2-hot)
    if (w == 0) {
        const int* e32 = (const int*)ei;
        int ok = 1;
#pragma unroll
        for (int k = 0; k < 4; ++k) {
            if (e32[2 * (lane * 4 + k) + 1] != 0) ok = 0;
        }
        int all0 = __all(ok);
        if (lane == 0) sflag[0] = all0;
    }
    if (tid < NBUCK) hist[tid] = 0;
    __syncthreads();
    const int is64 = sflag[0];

    const long long cb64 = (long long)blk * CHUNK;
    const unsigned n = (unsigned)(((E - cb64) < (long long)CHUNK) ? (E - cb64) : CHUNK);

    // pass 1: load edges ONCE into registers + histogram
    unsigned esrc[CHUNK / 1024], edst[CHUNK / 1024];
#pragma unroll
    for (int j = 0; j < CHUNK / 1024; ++j) {
        unsigned e = j * 1024 + tid;
        if (e < n) {
            esrc[j] = (unsigned)edge_at(ei, is64, cb64 + e);
            edst[j] = (unsigned)edge_at(ei, is64, E + cb64 + e);
            atomicAdd(&hist[edst[j] >> 8], 1u);
        }
    }
    __syncthreads();

    // inclusive scan of hist via wave shfl-scan + cross-wave fixup;
    // publish exclusive starts to lofs (b-major) for build.
    {
        unsigned v0 = (tid < NBUCK) ? hist[tid] : 0u;
        unsigned xx = v0;
#pragma unroll
        for (int off = 1; off < 64; off <<= 1) {
            unsigned t = __shfl_up(xx, off);
            if (lane >= off) xx += t;
        }
        if (lane == 63) wsum[w] = xx;
        __syncthreads();
        if (w == 0) {
            unsigned y = (lane < 16) ? wsum[lane] : 0u;
#pragma unroll
            for (int off = 1; off < 16; off <<= 1) {
                unsigned t = __shfl_up(y, off);
                if (lane >= off) y += t;
            }
            if (lane < 16) wsum[lane] = y;
        }
        __syncthreads();
        unsigned pre = (w > 0) ? wsum[w - 1] : 0u;
        if (tid < NBUCK) {
            unsigned ex = xx + pre - v0;
            lstart[tid] = ex;
            lofs[(unsigned)tid * (unsigned)npb + (unsigned)blk] = ex;
            hist[tid] = 0;   // reuse as cursor
        }
        if (tid == 0) lofs[(unsigned)NBUCK * (unsigned)npb + (unsigned)blk] = n;  // totals row
    }
    __syncthreads();

    // pass 2: scatter into LDS from registers, bucket-grouped
#pragma unroll
    for (int j = 0; j < CHUNK / 1024; ++j) {
        unsigned e = j * 1024 + tid;
        if (e < n) {
            unsigned d = edst[j];
            unsigned b = d >> 8;
            unsigned loc = atomicAdd(&hist[b], 1u);
            rec[lstart[b] + loc] = ((d & 255u) << 17) | esrc[j];
        }
    }
    __syncthreads();

    // pass 3: straight coalesced copy to block-local slab region
#pragma unroll
    for (int j = 0; j < CHUNK / 1024; ++j) {
        unsigned i = j * 1024 + tid;
        if (i < n) slab[(unsigned)blk * (unsigned)CHUNK + i] = rec[i];
    }
}

// Per-bucket fine CSR build: assemble bucket b's edges from all partition blocks'
// block-local slab regions (ranges from lofs), then LDS counting sort -> csr.
__global__ __launch_bounds__(256) void build_kernel(const unsigned* __restrict__ slab,
                                                    const unsigned* __restrict__ lofs,
                                                    int npb,
                                                    unsigned* __restrict__ deg,
                                                    float* __restrict__ invc,
                                                    unsigned* __restrict__ row_start,
                                                    int* __restrict__ csr) {
    __shared__ unsigned rstart[NBUCK];   // per-p source start within its chunk
    __shared__ unsigned rcnt[NBUCK];     // per-p count for this bucket
    __shared__ unsigned pofs[NBUCK];     // per-p dest offset in stage
    __shared__ unsigned redlds[4];
    __shared__ unsigned wsum2[4];
    __shared__ unsigned cnt[256];
    __shared__ unsigned stage[STAGECAP];

    const int tid = threadIdx.x;
    const int lane = tid & 63;
    const int w = tid >> 6;              // wave 0..3
    const int b = blockIdx.x;
    const int nb = b << 8;

    // load rows b and b+1 of lofs; es = sum of row b (global edges in buckets < b)
    unsigned psum = 0;
    for (int p = tid; p < npb; p += 256) {
        unsigned lo = lofs[(unsigned)b * (unsigned)npb + (unsigned)p];
        unsigned hi = lofs[(unsigned)(b + 1) * (unsigned)npb + (unsigned)p];
        rstart[p] = lo;
        rcnt[p] = hi - lo;
        psum += lo;
    }
#pragma unroll
    for (int off = 32; off >= 1; off >>= 1) psum += __shfl_xor(psum, off);
    if (lane == 0) redlds[w] = psum;
    __syncthreads();
    const unsigned es = redlds[0] + redlds[1] + redlds[2] + redlds[3];

    // exclusive scan of rcnt over p (wave 0, 64-wide rounds with carry)
    if (w == 0) {
        unsigned carry = 0;
        for (int r = 0; r < (npb + 63) / 64; ++r) {
            int p = r * 64 + lane;
            unsigned c = (p < npb) ? rcnt[p] : 0u;
            unsigned x = c;
#pragma unroll
            for (int off = 1; off < 64; off <<= 1) {
                unsigned t = __shfl_up(x, off);
                if (lane >= off) x += t;
            }
            if (p < npb) pofs[p] = x - c + carry;
            carry += __shfl(x, 63);
        }
    }
    __syncthreads();
    const unsigned n = pofs[npb - 1] + rcnt[npb - 1];

    // assemble bucket: thread t copies ranges for p = t, t+256, ...
    for (int p = tid; p < npb; p += 256) {
        unsigned src = (unsigned)p * (unsigned)CHUNK + rstart[p];
        unsigned dst = pofs[p];
        unsigned c = rcnt[p];
        for (unsigned i = 0; i < c; ++i)
            stage[dst + i] = slab[src + i];
    }
    __syncthreads();

    // counting sort over stage[0..n) (local node = rec>>17)
    cnt[tid] = 0;
    __syncthreads();
    for (unsigned i = tid; i < n; i += 256) {
        atomicAdd(&cnt[stage[i] >> 17], 1u);
    }
    __syncthreads();
    unsigned v = cnt[tid];
    unsigned x = v;
#pragma unroll
    for (int off = 1; off < 64; off <<= 1) {
        unsigned t = __shfl_up(x, off);
        if (lane >= off) x += t;
    }
    if (lane == 63) wsum2[w] = x;
    __syncthreads();
    unsigned pre = 0;
#pragma unroll
    for (int k = 0; k < 4; ++k) if (k < w) pre += wsum2[k];
    unsigned ex = x + pre - v;
    int node = nb + tid;
    if (node < N_NODES) {
        deg[node] = v;
        invc[node] = 1.0f / fmaxf((float)v, 1.0f);
        row_start[node] = es + ex;
    }
    __syncthreads();
    cnt[tid] = ex;   // reuse as cursor
    __syncthreads();
    for (unsigned i = tid; i < n; i += 256) {
        unsigned pr = stage[i];
        unsigned d = pr >> 17;
        unsigned pos = es + atomicAdd(&cnt[d], 1u);
        csr[pos] = (int)(pr & 0x1FFFFu);
    }
}

// Gather-mean over 128 fp8 cols -> bf16 agg: one wave per node.
// Lane = (slot s = lane>>4, colgroup cg = lane&15): lane loads uint2 (8 fp8 cols) of
// neighbor j+s -> 4 neighbors per wave-load; packed cvt+add (2 elems/instr).
__global__ __launch_bounds__(256) void gather_fp8_kernel(const unsigned char* __restrict__ featq,
                                                         const int* __restrict__ csr,
                                                         const unsigned* __restrict__ row_start,
                                                         const unsigned* __restrict__ deg,
                                                         const float* __restrict__ invc,
                                                         unsigned short* __restrict__ aggb) {
    const int wave = threadIdx.x >> 6;
    const int lane = threadIdx.x & 63;
    const int node = blockIdx.x * 4 + wave;
    if (node >= N_NODES) return;

    const unsigned start = row_start[node];
    const unsigned cnt = deg[node];
    const int s = lane >> 4;              // slot 0..3
    const unsigned cgo = (unsigned)((lane & 15) * 8);   // col-group byte offset

    floatx2 acc[4];
#pragma unroll
    for (int k = 0; k < 4; ++k) acc[k] = (floatx2){0.f, 0.f};

    for (unsigned base = 0; base < cnt; base += 64) {
        unsigned rem = cnt - base;
        if (rem > 64u) rem = 64u;
        int nid = (lane < (int)rem) ? csr[start + base + lane] : 0;
        for (unsigned j = 0; j < rem; j += 8) {
            uint2 u0 = {0u, 0u}, u1 = {0u, 0u};
            unsigned i0 = j + s;
            unsigned i1 = j + 4 + s;
            int s0 = __shfl(nid, (int)(i0 & 63));
            int s1 = __shfl(nid, (int)(i1 & 63));
            if (i0 < rem) u0 = *(const uint2*)&featq[((unsigned)s0 << 7) + cgo];
            if (i1 < rem) u1 = *(const uint2*)&featq[((unsigned)s1 << 7) + cgo];
            acc[0] += pkcvt<false>(u0.x); acc[1] += pkcvt<true>(u0.x);
            acc[2] += pkcvt<false>(u0.y); acc[3] += pkcvt<true>(u0.y);
            acc[0] += pkcvt<false>(u1.x); acc[1] += pkcvt<true>(u1.x);
            acc[2] += pkcvt<false>(u1.y); acc[3] += pkcvt<true>(u1.y);
        }
    }

    // reduce across the 4 slots (lanes differing in bits 4,5)
#pragma unroll
    for (int k = 0; k < 4; ++k) {
        acc[k][0] += __shfl_xor(acc[k][0], 16);
        acc[k][1] += __shfl_xor(acc[k][1], 16);
        acc[k][0] += __shfl_xor(acc[k][0], 32);
        acc[k][1] += __shfl_xor(acc[k][1], 32);
    }

    if (lane < 16) {
        const float ic = invc[node];
        uint4 o;
        o.x = packb(acc[0][0] * ic, acc[0][1] * ic);
        o.y = packb(acc[1][0] * ic, acc[1][1] * ic);
        o.z = packb(acc[2][0] * ic, acc[2][1] * ic);
        o.w = packb(acc[3][0] * ic, acc[3][1] * ic);
        *(uint4*)&aggb[(unsigned)node * 128u + cgo] = o;
    }
}

// Fused layer-1 GEMM + layer-2 projection: h = relu([aggb|xb]@wp1 + b1) stays in LDS,
// then [pq|q] = h@wp2 (+b2 on q half). 64 rows/block, 4 waves.
__global__ __launch_bounds__(256) void gemm12_kernel(const unsigned short* __restrict__ aggb,
                                                     const unsigned short* __restrict__ xb,
                                                     const unsigned short* __restrict__ wp1,
                                                     const float* __restrict__ b1,
                                                     const unsigned short* __restrict__ wp2,
                                                     const float* __restrict__ b2,
                                                     unsigned char* __restrict__ pq,
                                                     float* __restrict__ q) {
    __shared__ unsigned short sh[64][136];   // h rows (bf16), stride 272B (16B-aligned)
    const int wave = threadIdx.x >> 6;
    const int lane = threadIdx.x & 63;
    const int row0 = blockIdx.x * 64 + wave * 16;
    const unsigned abase = (unsigned)(row0 + (lane & 15)) * 128u + (unsigned)((lane >> 4) * 8);

    // ---- phase 1: h-strip via MFMA
    float4v acc[8];
#pragma unroll
    for (int ct = 0; ct < 8; ++ct) acc[ct] = (float4v){0.f, 0.f, 0.f, 0.f};

#pragma unroll
    for (int ks = 0; ks < 8; ++ks) {
        union { uint4 u; short8 s; } af;
        if (ks < 4) af.u = *(const uint4*)&aggb[abase + ks * 32];
        else        af.u = *(const uint4*)&xb[abase + (ks - 4) * 32];
#pragma unroll
        for (int ct = 0; ct < 8; ++ct) {
            union { uint4 u; short8 s; } bf;
            bf.u = *(const uint4*)&wp1[((ct * 8 + ks) * 64 + lane) * 8];
            acc[ct] = __builtin_amdgcn_mfma_f32_16x16x32_bf16(af.s, bf.s, acc[ct], 0, 0, 0);
        }
    }

    // relu+bias -> LDS (local rows of this wave's strip; no cross-wave sharing)
    const int lrow0 = wave * 16 + (lane >> 4) * 4;
    const int ccol = lane & 15;
#pragma unroll
    for (int ct = 0; ct < 8; ++ct) {
        const int col = ct * 16 + ccol;
        const float bv = b1[col];
#pragma unroll
        for (int r = 0; r < 4; ++r)
            sh[lrow0 + r][col] = f2b(fmaxf(acc[ct][r] + bv, 0.0f));
    }
    // wave-synchronous: each wave reads only rows it wrote; no __syncthreads needed.

    // ---- phase 2: [pq|q] strip via MFMA from LDS
    const unsigned short* aptr = &sh[wave * 16 + (lane & 15)][(lane >> 4) * 8];

    float4v acc2[5];
#pragma unroll
    for (int ct = 0; ct < 5; ++ct) acc2[ct] = (float4v){0.f, 0.f, 0.f, 0.f};

#pragma unroll
    for (int ks = 0; ks < 4; ++ks) {
        union { uint4 u; short8 s; } af;
        af.u = *(const uint4*)&aptr[ks * 32];
#pragma unroll
        for (int ct = 0; ct < 5; ++ct) {
            union { uint4 u; short8 s; } bf;
            bf.u = *(const uint4*)&wp2[((ct * 4 + ks) * 64 + lane) * 8];
            acc2[ct] = __builtin_amdgcn_mfma_f32_16x16x32_bf16(af.s, bf.s, acc2[ct], 0, 0, 0);
        }
    }

    const int crow0 = row0 + (lane >> 4) * 4;
#pragma unroll
    for (int ct = 0; ct < 5; ++ct) {
        const int col = ct * 16 + ccol;        // 0..79
#pragma unroll
        for (int r = 0; r < 4; ++r) {
            int row = crow0 + r;
            if (row < N_NODES) {
                if (col < D_OUT) {
                    pq[(unsigned)row * 40u + (unsigned)col] = f2q(acc2[ct][r]);
                } else {
                    q[(unsigned)row * 40u + (unsigned)(col - D_OUT)] = acc2[ct][r] + b2[col - D_OUT];
                }
            }
        }
    }
}

// out = log_softmax(meanagg(pq) + q): one wave per node.
// Lane = (slot s = lane/10, colgroup cg = lane%10): lane loads uint (4 fp8 cols) of
// neighbor j+s -> 6 neighbors per load instr; 4-deep unroll (24 neighbors/iter).
__global__ __launch_bounds__(256) void gather40_kernel(const unsigned char* __restrict__ pq,
                                                       const float* __restrict__ q,
                                                       const int* __restrict__ csr,
                                                       const unsigned* __restrict__ row_start,
                                                       const unsigned* __restrict__ deg,
                                                       const float* __restrict__ invc,
                                                       float* __restrict__ out) {
    __shared__ float sm[4][40];
    const int wave = threadIdx.x >> 6;
    const int lane = threadIdx.x & 63;
    const int node = blockIdx.x * 4 + wave;
    if (node >= N_NODES) return;

    const unsigned start = row_start[node];
    const unsigned cnt = deg[node];
    const int s = lane / 10;          // 0..6 (6 -> idle)
    const int cg = lane % 10;         // col group (4 cols)
    const unsigned cgo = (unsigned)(cg * 4);
    const bool gactive = s < 6;

    floatx2 a01 = (floatx2){0.f, 0.f}, a23 = (floatx2){0.f, 0.f};

    for (unsigned base = 0; base < cnt; base += 64) {
        unsigned rem = cnt - base;
        if (rem > 64u) rem = 64u;
        int nid = (lane < (int)rem) ? csr[start + base + lane] : 0;
        for (unsigned j = 0; j < rem; j += 24) {
            unsigned u[4];
#pragma unroll
            for (int t = 0; t < 4; ++t) {
                unsigned idx = j + t * 6 + s;
                int sid = __shfl(nid, (int)(idx & 63));
                bool valid = gactive && (idx < rem);
                u[t] = valid ? *(const unsigned*)&pq[(unsigned)sid * 40u + cgo] : 0u;
            }
#pragma unroll
            for (int t = 0; t < 4; ++t) {
                a01 += pkcvt<false>(u[t]);
                a23 += pkcvt<true>(u[t]);
            }
        }
    }

    float a0 = a01[0], a1 = a01[1], a2 = a23[0], a3 = a23[1];
    // reduce slots 0..5 into slot 0 (lanes 0..9), guarded to avoid pollution
    {
        float t0, t1, t2, t3;
        t0 = __shfl(a0, lane + 30); t1 = __shfl(a1, lane + 30);
        t2 = __shfl(a2, lane + 30); t3 = __shfl(a3, lane + 30);
        if (lane < 30) { a0 += t0; a1 += t1; a2 += t2; a3 += t3; }
        t0 = __shfl(a0, lane + 20); t1 = __shfl(a1, lane + 20);
        t2 = __shfl(a2, lane + 20); t3 = __shfl(a3, lane + 20);
        if (lane < 10) { a0 += t0; a1 += t1; a2 += t2; a3 += t3; }
        t0 = __shfl(a0, lane + 10); t1 = __shfl(a1, lane + 10);
        t2 = __shfl(a2, lane + 10); t3 = __shfl(a3, lane + 10);
        if (lane < 10) { a0 += t0; a1 += t1; a2 += t2; a3 += t3; }
    }
    if (lane < 10) {
        sm[wave][cg * 4 + 0] = a0;
        sm[wave][cg * 4 + 1] = a1;
        sm[wave][cg * 4 + 2] = a2;
        sm[wave][cg * 4 + 3] = a3;
    }
    // wave-synchronous LDS round-trip (no barrier needed within a wave)
    const bool active = lane < D_OUT;
    float v = active ? (sm[wave][active ? lane : 0] * invc[node]
                        + q[(unsigned)node * 40u + (unsigned)(active ? lane : 0)])
                     : -__builtin_huge_valf();
    float m = v;
#pragma unroll
    for (int off = 32; off >= 1; off >>= 1) m = fmaxf(m, __shfl_xor(m, off));
    float e = active ? expf(v - m) : 0.0f;
    float ssum = e;
#pragma unroll
    for (int off = 32; off >= 1; off >>= 1) ssum += __shfl_xor(ssum, off);
    float ls = logf(ssum);
    if (active) out[(unsigned)node * 40u + (unsigned)lane] = v - m - ls;
}

extern "C" void kernel_launch(void* const* d_in, const int* in_sizes, int n_in,
                              void* d_out, int out_size, void* d_ws, size_t ws_size,
                              hipStream_t stream) {
    const float* x   = (const float*)d_in[0];
    const void*  ei  = d_in[1];
    const float* W1l = (const float*)d_in[2];
    const float* W1r = (const float*)d_in[3];
    const float* b1  = (const float*)d_in[4];
    const float* W2l = (const float*)d_in[5];
    const float* W2r = (const float*)d_in[6];
    const float* b2  = (const float*)d_in[7];
    float* out = (float*)d_out;

    const long long E = (long long)in_sizes[1] / 2;
    const int NPB = (int)((E + CHUNK - 1) / CHUNK);

    char* ws = (char*)d_ws;
    unsigned* deg       = (unsigned*)(ws + 16384);
    float*    invc      = (float*)(ws + 416384);
    unsigned* row_start = (unsigned*)(ws + 816384);
    int*      csr       = (int*)(ws + 1216384);
    unsigned short* xb  = (unsigned short*)(ws + 14016384);
    unsigned short* aggb= (unsigned short*)(ws + 39616384);
    unsigned* slab      = (unsigned*)(ws + 39616384);        // alias (dead before aggb written)
    unsigned short* wp1 = (unsigned short*)(ws + 65216384);
    unsigned short* wp2 = (unsigned short*)(ws + 65281920);
    unsigned char*  pq  = (unsigned char*)(ws + 65310720);
    float*    q         = (float*)(ws + 69310720);
    unsigned char*  xq  = (unsigned char*)(ws + 90910720);
    unsigned* lofs      = (unsigned*)(ws + 103710720);

    // mega: partition-blocks first (build depends on them), then cast + pack_w
    mega_kernel<<<NPB + CAST_BLOCKS_1K + 6, 1024, 0, stream>>>(
        ei, slab, lofs, E, NPB,
        x, xb, xq, W1l, W1r, W2l, W2r, wp1, wp2);

    build_kernel<<<NBUCK, 256, 0, stream>>>(slab, lofs, NPB, deg, invc, row_start, csr);

    // layer 1: fp8 gather-mean of x, then fused GEMM1+GEMM2 (h stays in LDS)
    gather_fp8_kernel<<<(N_NODES + 3) / 4, 256, 0, stream>>>(xq, csr, row_start, deg, invc, aggb);
    gemm12_kernel<<<(N_NODES + 63) / 64, 256, 0, stream>>>(aggb, xb, wp1, b1, wp2, b2, pq, q);

    // layer 2 gather-mean + log_softmax
    gather40_kernel<<<(N_NODES + 3) / 4, 256, 0, stream>>>(pq, q, csr, row_start, deg, invc, out);
}